// Round 2
// baseline (718.159 us; speedup 1.0000x reference)
//
#include <hip/hip_runtime.h>
#include <hip/hip_bf16.h>
#include <cstdint>

typedef __attribute__((ext_vector_type(8))) short short8;
typedef __attribute__((ext_vector_type(4))) float floatx4;
typedef __attribute__((ext_vector_type(2))) float floatx2;

__device__ __forceinline__ float tanh_fast(float x) {
    float e = __expf(2.0f * x);                            // v_exp_f32 path
    return 1.0f - 2.0f * __builtin_amdgcn_rcpf(e + 1.0f);  // saturates to +-1
}

__device__ __forceinline__ unsigned int bf16_bits(float f) {
    __hip_bfloat16 h = __float2bfloat16(f);   // RNE
    return (unsigned int)*reinterpret_cast<unsigned short*>(&h);
}
__device__ __forceinline__ unsigned int pack2(float lo, float hi) {
    return bf16_bits(lo) | (bf16_bits(hi) << 16);
}

// LDS tiles: 128 rows x 64 k (bf16), row stride 72 shorts (144 B pad).
// Single-buffered (36 KB) so LDS allows 4 blocks/CU; pipelining is done by
// prefetching the next K-tile into REGISTERS during the MFMA phase (T14).
#define LDS_STRIDE 72

// XCD-aware bijective block swizzle (requires nwg % 8 == 0, gridDim.x == 8).
// XCD k (= flat % 8 under round-robin dispatch) gets a contiguous run of
// row-panels with col varying fastest -> the 8 col-blocks sharing an A-panel
// are co-resident on ONE XCD L2 instead of spread over 8.
__device__ __forceinline__ void swizzle_tile(int& row0, int& col0) {
    const int nwg  = gridDim.x * gridDim.y;
    const int flat = blockIdx.y * gridDim.x + blockIdx.x;
    const int swz  = (flat & 7) * (nwg >> 3) + (flat >> 3);
    col0 = (swz & 7) * 128;
    row0 = (swz >> 3) * 128;
}

// ---------------------------------------------------------------------------
// K1: out[0:pivot] = tanh(x @ W^T + b)   (f32 in, bf16 MFMA, f32 out)
// ---------------------------------------------------------------------------
__global__ __launch_bounds__(256, 3) void k1_gemm_tanh(
    const float* __restrict__ X,
    const float* __restrict__ W,
    const float* __restrict__ Bv,
    float* __restrict__ out,
    int K)
{
    __shared__ __align__(16) short As[128 * LDS_STRIDE];
    __shared__ __align__(16) short Bs[128 * LDS_STRIDE];

    const int tid  = threadIdx.x;
    const int lane = tid & 63;
    const int wave = tid >> 6;
    const int wm = wave & 1, wn = wave >> 1;

    int row0, col0;
    swizzle_tile(row0, col0);

    const int l15  = lane & 15;
    const int quad = lane >> 4;
    const int a_base = (wm * 64 + l15) * LDS_STRIDE;
    const int b_base = (wn * 64 + l15) * LDS_STRIDE;

    // staging geometry: 128 rows x 16 float4-cols, thread -> (sr, sc)
    const int sr = tid >> 4;      // row within 16-row group
    const int sc = tid & 15;      // float4 column
    const float* Xp = X + (size_t)(row0 + sr) * K + sc * 4;
    const float* Wp = W + (size_t)(col0 + sr) * K + sc * 4;

    floatx4 acc[4][4];
#pragma unroll
    for (int a = 0; a < 4; ++a)
#pragma unroll
        for (int b = 0; b < 4; ++b) acc[a][b] = (floatx4){0.f, 0.f, 0.f, 0.f};

    float4 pa[8], pb[8];

#pragma unroll
    for (int i = 0; i < 8; ++i) {           // prologue: loads for k0 = 0
        pa[i] = *(const float4*)(Xp + (size_t)i * 16 * K);
        pb[i] = *(const float4*)(Wp + (size_t)i * 16 * K);
    }

    for (int k0 = 0; k0 < K; k0 += 64) {
        __syncthreads();                    // all reads of LDS tile done
        // cvt + ds_write current tile (vmcnt wait lands here)
#pragma unroll
        for (int i = 0; i < 8; ++i) {
            const int r = i * 16 + sr;
            uint2 ea, eb;
            ea.x = pack2(pa[i].x, pa[i].y); ea.y = pack2(pa[i].z, pa[i].w);
            eb.x = pack2(pb[i].x, pb[i].y); eb.y = pack2(pb[i].z, pb[i].w);
            *(uint2*)&As[r * LDS_STRIDE + sc * 4] = ea;
            *(uint2*)&Bs[r * LDS_STRIDE + sc * 4] = eb;
        }
        // issue next tile's loads NOW -> in flight across the MFMA phase
        if (k0 + 64 < K) {
#pragma unroll
            for (int i = 0; i < 8; ++i) {
                pa[i] = *(const float4*)(Xp + (size_t)i * 16 * K + k0 + 64);
                pb[i] = *(const float4*)(Wp + (size_t)i * 16 * K + k0 + 64);
            }
        }
        __syncthreads();                    // LDS tile ready
#pragma unroll
        for (int ki = 0; ki < 2; ++ki) {
            const int kx = ki * 32 + quad * 8;
            short8 af[4], bf[4];
#pragma unroll
            for (int s = 0; s < 4; ++s)
                af[s] = *(const short8*)&As[a_base + s * 16 * LDS_STRIDE + kx];
#pragma unroll
            for (int s = 0; s < 4; ++s)
                bf[s] = *(const short8*)&Bs[b_base + s * 16 * LDS_STRIDE + kx];
#pragma unroll
            for (int a = 0; a < 4; ++a)
#pragma unroll
                for (int b = 0; b < 4; ++b)
                    acc[a][b] = __builtin_amdgcn_mfma_f32_16x16x32_bf16(
                        af[a], bf[b], acc[a][b], 0, 0, 0);
        }
    }

    float bv[4];
#pragma unroll
    for (int b = 0; b < 4; ++b)
        bv[b] = Bv[col0 + wn * 64 + b * 16 + l15];

#pragma unroll
    for (int a = 0; a < 4; ++a) {
        const int rbase = row0 + wm * 64 + a * 16 + quad * 4;
#pragma unroll
        for (int b = 0; b < 4; ++b) {
            const int n = col0 + wn * 64 + b * 16 + l15;
#pragma unroll
            for (int r = 0; r < 4; ++r)
                __builtin_nontemporal_store(
                    tanh_fast(acc[a][b][r] + bv[b]),
                    &out[(size_t)(rbase + r) * 1024 + n]);
        }
    }
}

// ---------------------------------------------------------------------------
// K2: C2 = M @ W^T,  M[2p+kk, j] = G[p][2j+kk]  (de-interleave at staging)
// out[pivot + 2p + (i>=512)][(2i+kk)%1024] = (1 - h[p,i]^2) * C2[2p+kk, i]
// ---------------------------------------------------------------------------
__global__ __launch_bounds__(256, 3) void k2_gemm_jac(
    const float* __restrict__ G,      // x_Jx + pivot*1024, rows of 2048 floats
    const float* __restrict__ W,
    const float* __restrict__ Hout,   // hAx (f32) = out rows [0, pivot)
    float* __restrict__ out2,         // out + pivot*1024
    int K)
{
    __shared__ __align__(16) short As[128 * LDS_STRIDE];
    __shared__ __align__(16) short Bs[128 * LDS_STRIDE];

    const int tid  = threadIdx.x;
    const int lane = tid & 63;
    const int wave = tid >> 6;
    const int wm = wave & 1, wn = wave >> 1;

    int r0, col0;
    swizzle_tile(r0, col0);               // r0 = M-row base (r = 2p+kk)
    const int p0 = r0 >> 1;

    const int l15  = lane & 15;
    const int quad = lane >> 4;
    const int a_base = (wm * 64 + l15) * LDS_STRIDE;
    const int b_base = (wn * 64 + l15) * LDS_STRIDE;

    const int sr = tid >> 4;
    const int sc = tid & 15;
    const float* Wp = W + (size_t)(col0 + sr) * K + sc * 4;
    const float* Gp = G + (size_t)(p0 + sr) * 2048 + sc * 8;

    floatx4 acc[4][4];
#pragma unroll
    for (int a = 0; a < 4; ++a)
#pragma unroll
        for (int b = 0; b < 4; ++b) acc[a][b] = (floatx4){0.f, 0.f, 0.f, 0.f};

    float4 pb[8];          // W tile
    float4 qa[4][2];       // G pair-rows: 64 pair-rows x 16 chunks of 8 floats

#pragma unroll
    for (int i = 0; i < 8; ++i)
        pb[i] = *(const float4*)(Wp + (size_t)i * 16 * K);
#pragma unroll
    for (int i = 0; i < 4; ++i) {
        const float* src = Gp + (size_t)i * 16 * 2048;
        qa[i][0] = *(const float4*)src;
        qa[i][1] = *(const float4*)(src + 4);
    }

    for (int k0 = 0; k0 < K; k0 += 64) {
        __syncthreads();
        // B: W tile, same as K1
#pragma unroll
        for (int i = 0; i < 8; ++i) {
            const int r = i * 16 + sr;
            uint2 eb;
            eb.x = pack2(pb[i].x, pb[i].y); eb.y = pack2(pb[i].z, pb[i].w);
            *(uint2*)&Bs[r * LDS_STRIDE + sc * 4] = eb;
        }
        // A: de-interleave [j0k0 j0k1 j1k0 j1k1 ...] -> rows 2q / 2q+1
#pragma unroll
        for (int i = 0; i < 4; ++i) {
            const int q = i * 16 + sr;
            uint2 E, O;
            E.x = pack2(qa[i][0].x, qa[i][0].z); E.y = pack2(qa[i][1].x, qa[i][1].z);
            O.x = pack2(qa[i][0].y, qa[i][0].w); O.y = pack2(qa[i][1].y, qa[i][1].w);
            *(uint2*)&As[(2 * q)     * LDS_STRIDE + sc * 4] = E;
            *(uint2*)&As[(2 * q + 1) * LDS_STRIDE + sc * 4] = O;
        }
        // prefetch next K-tile into registers during the MFMA phase
        if (k0 + 64 < K) {
#pragma unroll
            for (int i = 0; i < 8; ++i)
                pb[i] = *(const float4*)(Wp + (size_t)i * 16 * K + k0 + 64);
#pragma unroll
            for (int i = 0; i < 4; ++i) {
                const float* src = Gp + (size_t)i * 16 * 2048 + 2 * (k0 + 64);
                qa[i][0] = *(const float4*)src;
                qa[i][1] = *(const float4*)(src + 4);
            }
        }
        __syncthreads();
#pragma unroll
        for (int ki = 0; ki < 2; ++ki) {
            const int kx = ki * 32 + quad * 8;
            short8 af[4], bf[4];
#pragma unroll
            for (int s = 0; s < 4; ++s)
                af[s] = *(const short8*)&As[a_base + s * 16 * LDS_STRIDE + kx];
#pragma unroll
            for (int s = 0; s < 4; ++s)
                bf[s] = *(const short8*)&Bs[b_base + s * 16 * LDS_STRIDE + kx];
#pragma unroll
            for (int a = 0; a < 4; ++a)
#pragma unroll
                for (int b = 0; b < 4; ++b)
                    acc[a][b] = __builtin_amdgcn_mfma_f32_16x16x32_bf16(
                        af[a], bf[b], acc[a][b], 0, 0, 0);
        }
    }

    // epilogue: acc regs (0,1)/(2,3) are M-rows (2p, 2p+1) -> one float2 store
#pragma unroll
    for (int a = 0; a < 4; ++a) {
        const int rb = r0 + wm * 64 + a * 16 + quad * 4;   // even
#pragma unroll
        for (int b = 0; b < 4; ++b) {
            const int i = col0 + wn * 64 + b * 16 + l15;
            const int shift = (i >= 512) ? 1 : 0;
            const int ccol = 2 * i - shift * 1024;
#pragma unroll
            for (int pr = 0; pr < 2; ++pr) {
                const int re = rb + pr * 2;                // even row = 2p
                const int p  = re >> 1;
                const float h  = __builtin_nontemporal_load(
                                     &Hout[(size_t)p * 1024 + i]);
                const float hp = 1.0f - h * h;
                floatx2 st;
                st.x = hp * acc[a][b][pr * 2];             // kk=0 -> col 2i
                st.y = hp * acc[a][b][pr * 2 + 1];         // kk=1 -> col 2i+1
                __builtin_nontemporal_store(
                    st, (floatx2*)&out2[(size_t)(re + shift) * 1024 + ccol]);
            }
        }
    }
}

extern "C" void kernel_launch(void* const* d_in, const int* in_sizes, int n_in,
                              void* d_out, int out_size, void* d_ws, size_t ws_size,
                              hipStream_t stream) {
    const float* xJx = (const float*)d_in[0];
    const float* W   = (const float*)d_in[1];
    const float* bv  = (const float*)d_in[2];
    float* out = (float*)d_out;

    const int C     = 1024;
    const int rows3 = in_sizes[0] / C;   // 3*pivot
    const int pivot = rows3 / 3;         // 16384

    dim3 blk(256);
    dim3 g1(C / 128, pivot / 128);       // 8 x 128 = 1024 blocks (nwg%8==0)
    k1_gemm_tanh<<<g1, blk, 0, stream>>>(xJx, W, bv, out, C);

    dim3 g2(C / 128, (2 * pivot) / 128); // 8 x 256 = 2048 blocks (nwg%8==0)
    k2_gemm_jac<<<g2, blk, 0, stream>>>(xJx + (size_t)pivot * C, W, out,
                                        out + (size_t)pivot * C, C);
}

// Round 3
// 526.302 us; speedup vs baseline: 1.3645x; 1.3645x over previous
//
#include <hip/hip_runtime.h>
#include <hip/hip_bf16.h>
#include <cstdint>

typedef __attribute__((ext_vector_type(8))) short short8;
typedef __attribute__((ext_vector_type(4))) float floatx4;

__device__ __forceinline__ float tanh_fast(float x) {
    float e = __expf(2.0f * x);                            // v_exp_f32 path
    return 1.0f - 2.0f * __builtin_amdgcn_rcpf(e + 1.0f);  // saturates to +-1
}

__device__ __forceinline__ unsigned int bf16_bits(float f) {
    __hip_bfloat16 h = __float2bfloat16(f);   // RNE
    return (unsigned int)*reinterpret_cast<unsigned short*>(&h);
}
__device__ __forceinline__ unsigned int pack2(float lo, float hi) {
    return bf16_bits(lo) | (bf16_bits(hi) << 16);
}

// LDS tiles: 128 rows x 64 k (bf16), row stride 72 shorts (144 B pad).
// ds_write_b64 staging: 4 lanes per 8B span  = wave64 floor (conflict-free).
// ds_read_b128 frags:   8 lanes per 16B span = wave64 floor (conflict-free).
#define LDS_STRIDE 72

// XCD-aware bijective block swizzle (VALIDATED R2: k1 FETCH 78 MB ~= ideal 68).
// Requires nwg % 8 == 0, gridDim.x == 8. XCD k (= flat % 8 under round-robin
// dispatch) gets a contiguous run of row-panels with col varying fastest ->
// the 8 col-blocks sharing an A-panel are co-resident on ONE XCD L2.
__device__ __forceinline__ void swizzle_tile(int& row0, int& col0) {
    const int nwg  = gridDim.x * gridDim.y;
    const int flat = blockIdx.y * gridDim.x + blockIdx.x;
    const int swz  = (flat & 7) * (nwg >> 3) + (flat >> 3);
    col0 = (swz & 7) * 128;
    row0 = (swz >> 3) * 128;
}

// ---------------------------------------------------------------------------
// K1: out[0:pivot] = tanh(x @ W^T + b)   (f32 in, bf16 MFMA, f32 out)
// ---------------------------------------------------------------------------
__global__ __launch_bounds__(256) void k1_gemm_tanh(
    const float* __restrict__ X,
    const float* __restrict__ W,
    const float* __restrict__ Bv,
    float* __restrict__ out,
    int K)
{
    __shared__ __align__(16) short As[128 * LDS_STRIDE];
    __shared__ __align__(16) short Bs[128 * LDS_STRIDE];

    const int tid  = threadIdx.x;
    const int lane = tid & 63;
    const int wave = tid >> 6;
    const int wm = wave & 1, wn = wave >> 1;

    int row0, col0;
    swizzle_tile(row0, col0);

    const int l15  = lane & 15;
    const int quad = lane >> 4;
    const int a_base = (wm * 64 + l15) * LDS_STRIDE;
    const int b_base = (wn * 64 + l15) * LDS_STRIDE;

    floatx4 acc[4][4];
#pragma unroll
    for (int a = 0; a < 4; ++a)
#pragma unroll
        for (int b = 0; b < 4; ++b) acc[a][b] = (floatx4){0.f, 0.f, 0.f, 0.f};

    for (int k0 = 0; k0 < K; k0 += 64) {
        __syncthreads();
#pragma unroll
        for (int i = 0; i < 8; ++i) {
            const int g = i * 256 + tid;
            const int r = g >> 4, c = g & 15;      // 128 rows x 16 float4-cols
            const float4 va = *(const float4*)(X + (size_t)(row0 + r) * K + k0 + c * 4);
            const float4 vb = *(const float4*)(W + (size_t)(col0 + r) * K + k0 + c * 4);
            uint2 ea, eb;
            ea.x = pack2(va.x, va.y); ea.y = pack2(va.z, va.w);
            eb.x = pack2(vb.x, vb.y); eb.y = pack2(vb.z, vb.w);
            *(uint2*)&As[r * LDS_STRIDE + c * 4] = ea;
            *(uint2*)&Bs[r * LDS_STRIDE + c * 4] = eb;
        }
        __syncthreads();
#pragma unroll
        for (int ki = 0; ki < 2; ++ki) {
            const int kx = ki * 32 + quad * 8;
            short8 af[4], bf[4];
#pragma unroll
            for (int s = 0; s < 4; ++s)
                af[s] = *(const short8*)&As[a_base + s * 16 * LDS_STRIDE + kx];
#pragma unroll
            for (int s = 0; s < 4; ++s)
                bf[s] = *(const short8*)&Bs[b_base + s * 16 * LDS_STRIDE + kx];
#pragma unroll
            for (int a = 0; a < 4; ++a)
#pragma unroll
                for (int b = 0; b < 4; ++b)
                    acc[a][b] = __builtin_amdgcn_mfma_f32_16x16x32_bf16(
                        af[a], bf[b], acc[a][b], 0, 0, 0);
        }
    }

    float bv[4];
#pragma unroll
    for (int b = 0; b < 4; ++b)
        bv[b] = Bv[col0 + wn * 64 + b * 16 + l15];

#pragma unroll
    for (int a = 0; a < 4; ++a) {
        const int rbase = row0 + wm * 64 + a * 16 + quad * 4;
#pragma unroll
        for (int b = 0; b < 4; ++b) {
            const int n = col0 + wn * 64 + b * 16 + l15;
#pragma unroll
            for (int r = 0; r < 4; ++r)
                out[(size_t)(rbase + r) * 1024 + n] = tanh_fast(acc[a][b][r] + bv[b]);
        }
    }
}

// ---------------------------------------------------------------------------
// K2: C2 = M @ W^T,  M[2p+kk, j] = G[p][2j+kk]  (de-interleave at staging)
// out[pivot + 2p + (i>=512)][(2i+kk)%1024] = (1 - h[p,i]^2) * C2[2p+kk, i]
// ---------------------------------------------------------------------------
__global__ __launch_bounds__(256) void k2_gemm_jac(
    const float* __restrict__ G,      // x_Jx + pivot*1024, rows of 2048 floats
    const float* __restrict__ W,
    const float* __restrict__ Hout,   // hAx (f32) = out rows [0, pivot)
    float* __restrict__ out2,         // out + pivot*1024
    int K)
{
    __shared__ __align__(16) short As[128 * LDS_STRIDE];
    __shared__ __align__(16) short Bs[128 * LDS_STRIDE];

    const int tid  = threadIdx.x;
    const int lane = tid & 63;
    const int wave = tid >> 6;
    const int wm = wave & 1, wn = wave >> 1;

    int r0, col0;
    swizzle_tile(r0, col0);               // r0 = M-row base (r = 2p+kk)
    const int p0 = r0 >> 1;

    const int l15  = lane & 15;
    const int quad = lane >> 4;
    const int a_base = (wm * 64 + l15) * LDS_STRIDE;
    const int b_base = (wn * 64 + l15) * LDS_STRIDE;

    floatx4 acc[4][4];
#pragma unroll
    for (int a = 0; a < 4; ++a)
#pragma unroll
        for (int b = 0; b < 4; ++b) acc[a][b] = (floatx4){0.f, 0.f, 0.f, 0.f};

    for (int k0 = 0; k0 < K; k0 += 64) {
        __syncthreads();
        // B: W tile, same as K1
#pragma unroll
        for (int i = 0; i < 8; ++i) {
            const int g = i * 256 + tid;
            const int r = g >> 4, c = g & 15;
            const float4 vb = *(const float4*)(W + (size_t)(col0 + r) * K + k0 + c * 4);
            uint2 eb;
            eb.x = pack2(vb.x, vb.y); eb.y = pack2(vb.z, vb.w);
            *(uint2*)&Bs[r * LDS_STRIDE + c * 4] = eb;
        }
        // A: 64 pair-rows x 16 chunks of 8 floats (=4 channels x 2 jac-cols)
#pragma unroll
        for (int i = 0; i < 4; ++i) {
            const int g = i * 256 + tid;
            const int q = g >> 4, d = g & 15;   // q: pair-row 0..63, d: chunk
            const float* src = G + (size_t)(p0 + q) * 2048 + 2 * k0 + d * 8;
            const float4 u0 = *(const float4*)src;        // [j0k0 j0k1 j1k0 j1k1]
            const float4 u1 = *(const float4*)(src + 4);  // [j2k0 j2k1 j3k0 j3k1]
            uint2 E, O;
            E.x = pack2(u0.x, u0.z); E.y = pack2(u1.x, u1.z);   // kk=0 -> row 2q
            O.x = pack2(u0.y, u0.w); O.y = pack2(u1.y, u1.w);   // kk=1 -> row 2q+1
            *(uint2*)&As[(2 * q)     * LDS_STRIDE + d * 4] = E;
            *(uint2*)&As[(2 * q + 1) * LDS_STRIDE + d * 4] = O;
        }
        __syncthreads();
#pragma unroll
        for (int ki = 0; ki < 2; ++ki) {
            const int kx = ki * 32 + quad * 8;
            short8 af[4], bf[4];
#pragma unroll
            for (int s = 0; s < 4; ++s)
                af[s] = *(const short8*)&As[a_base + s * 16 * LDS_STRIDE + kx];
#pragma unroll
            for (int s = 0; s < 4; ++s)
                bf[s] = *(const short8*)&Bs[b_base + s * 16 * LDS_STRIDE + kx];
#pragma unroll
            for (int a = 0; a < 4; ++a)
#pragma unroll
                for (int b = 0; b < 4; ++b)
                    acc[a][b] = __builtin_amdgcn_mfma_f32_16x16x32_bf16(
                        af[a], bf[b], acc[a][b], 0, 0, 0);
        }
    }

    // epilogue: acc regs (0,1)/(2,3) are M-rows (2p, 2p+1) -> one float2 store
#pragma unroll
    for (int a = 0; a < 4; ++a) {
        const int rb = r0 + wm * 64 + a * 16 + quad * 4;   // even
#pragma unroll
        for (int b = 0; b < 4; ++b) {
            const int i = col0 + wn * 64 + b * 16 + l15;
            const int shift = (i >= 512) ? 1 : 0;
            const int ccol = 2 * i - shift * 1024;
#pragma unroll
            for (int pr = 0; pr < 2; ++pr) {
                const int re = rb + pr * 2;                // even row = 2p
                const int p  = re >> 1;
                const float h  = Hout[(size_t)p * 1024 + i];
                const float hp = 1.0f - h * h;
                float2 st;
                st.x = hp * acc[a][b][pr * 2];             // kk=0 -> col 2i
                st.y = hp * acc[a][b][pr * 2 + 1];         // kk=1 -> col 2i+1
                *(float2*)&out2[(size_t)(re + shift) * 1024 + ccol] = st;
            }
        }
    }
}

extern "C" void kernel_launch(void* const* d_in, const int* in_sizes, int n_in,
                              void* d_out, int out_size, void* d_ws, size_t ws_size,
                              hipStream_t stream) {
    const float* xJx = (const float*)d_in[0];
    const float* W   = (const float*)d_in[1];
    const float* bv  = (const float*)d_in[2];
    float* out = (float*)d_out;

    const int C     = 1024;
    const int rows3 = in_sizes[0] / C;   // 3*pivot
    const int pivot = rows3 / 3;         // 16384

    dim3 blk(256);
    dim3 g1(C / 128, pivot / 128);       // 8 x 128 = 1024 blocks (nwg%8==0)
    k1_gemm_tanh<<<g1, blk, 0, stream>>>(xJx, W, bv, out, C);

    dim3 g2(C / 128, (2 * pivot) / 128); // 8 x 256 = 2048 blocks (nwg%8==0)
    k2_gemm_jac<<<g2, blk, 0, stream>>>(xJx + (size_t)pivot * C, W, out,
                                        out + (size_t)pivot * C, C);
}

// Round 4
// 520.251 us; speedup vs baseline: 1.3804x; 1.0116x over previous
//
#include <hip/hip_runtime.h>
#include <hip/hip_bf16.h>
#include <cstdint>

typedef __attribute__((ext_vector_type(8))) short short8;
typedef __attribute__((ext_vector_type(4))) float floatx4;

__device__ __forceinline__ float tanh_fast(float x) {
    float e = __expf(2.0f * x);                            // v_exp_f32 path
    return 1.0f - 2.0f * __builtin_amdgcn_rcpf(e + 1.0f);  // saturates to +-1
}

__device__ __forceinline__ unsigned int bf16_bits(float f) {
    __hip_bfloat16 h = __float2bfloat16(f);   // RNE
    return (unsigned int)*reinterpret_cast<unsigned short*>(&h);
}
__device__ __forceinline__ unsigned int pack2(float lo, float hi) {
    return bf16_bits(lo) | (bf16_bits(hi) << 16);
}

// async global->LDS, 16 B per lane. LDS dest is wave-uniform base + lane*16.
__device__ __forceinline__ void async16(const void* g, void* l) {
    __builtin_amdgcn_global_load_lds(
        (const __attribute__((address_space(1))) unsigned int*)g,
        (__attribute__((address_space(3))) unsigned int*)l, 16, 0, 0);
}

// XCD-aware bijective block swizzle (VALIDATED: k1 FETCH 78 MB ~ ideal, k2
// 565->165 MB). Requires nwg % 8 == 0, gridDim.x == 8.
__device__ __forceinline__ void swizzle_tile(int& row0, int& col0) {
    const int nwg  = gridDim.x * gridDim.y;
    const int flat = blockIdx.y * gridDim.x + blockIdx.x;
    const int swz  = (flat & 7) * (nwg >> 3) + (flat >> 3);
    col0 = (swz & 7) * 128;
    row0 = (swz >> 3) * 128;
}

// ===========================================================================
// FAST PATH (needs 98 MB workspace): bf16 pre-pass + m97-style GEMMs
// ===========================================================================

// ---------------------------------------------------------------------------
// cvt_prep: X(f32)->Xb(bf16); G(f32, interleaved)->Mb(bf16, de-interleaved
// M[2p+kk][j] = G[p][2j+kk]); W(f32)->Wb(bf16). 16 f32/thread.
// ---------------------------------------------------------------------------
__global__ __launch_bounds__(256) void cvt_prep(
    const float* __restrict__ X, const float* __restrict__ G,
    const float* __restrict__ W,
    short* __restrict__ Xb, short* __restrict__ Mb, short* __restrict__ Wb,
    int nbX, int nbG)
{
    const int tid = threadIdx.x;
    const int b   = blockIdx.x;
    if (b < nbX) {                       // ---- X straight convert
        const size_t e = ((size_t)b * 256 + tid) * 16;
        const float4 f0 = *(const float4*)(X + e);
        const float4 f1 = *(const float4*)(X + e + 4);
        const float4 f2 = *(const float4*)(X + e + 8);
        const float4 f3 = *(const float4*)(X + e + 12);
        uint4 o0, o1;
        o0.x = pack2(f0.x, f0.y); o0.y = pack2(f0.z, f0.w);
        o0.z = pack2(f1.x, f1.y); o0.w = pack2(f1.z, f1.w);
        o1.x = pack2(f2.x, f2.y); o1.y = pack2(f2.z, f2.w);
        o1.z = pack2(f3.x, f3.y); o1.w = pack2(f3.z, f3.w);
        *(uint4*)(Xb + e)     = o0;
        *(uint4*)(Xb + e + 8) = o1;
    } else if (b < nbX + nbG) {          // ---- G de-interleave
        const size_t s = (size_t)(b - nbX) * 256 + tid;  // 16-float segment
        const size_t p = s >> 7;                         // G row (pair-row)
        const int    c = (int)(s & 127);                 // segment in row
        const float* src = G + p * 2048 + (size_t)c * 16;
        const float4 f0 = *(const float4*)(src);         // [j0k0 j0k1 j1k0 j1k1]
        const float4 f1 = *(const float4*)(src + 4);
        const float4 f2 = *(const float4*)(src + 8);
        const float4 f3 = *(const float4*)(src + 12);
        uint4 E, O;
        E.x = pack2(f0.x, f0.z); E.y = pack2(f1.x, f1.z);
        E.z = pack2(f2.x, f2.z); E.w = pack2(f3.x, f3.z);
        O.x = pack2(f0.y, f0.w); O.y = pack2(f1.y, f1.w);
        O.z = pack2(f2.y, f2.w); O.w = pack2(f3.y, f3.w);
        *(uint4*)(Mb + (2 * p)     * 1024 + (size_t)c * 8) = E;   // kk=0
        *(uint4*)(Mb + (2 * p + 1) * 1024 + (size_t)c * 8) = O;   // kk=1
    } else {                             // ---- W straight convert
        const size_t e = ((size_t)(b - nbX - nbG) * 256 + tid) * 16;
        const float4 f0 = *(const float4*)(W + e);
        const float4 f1 = *(const float4*)(W + e + 4);
        const float4 f2 = *(const float4*)(W + e + 8);
        const float4 f3 = *(const float4*)(W + e + 12);
        uint4 o0, o1;
        o0.x = pack2(f0.x, f0.y); o0.y = pack2(f0.z, f0.w);
        o0.z = pack2(f1.x, f1.y); o0.w = pack2(f1.z, f1.w);
        o1.x = pack2(f2.x, f2.y); o1.y = pack2(f2.z, f2.w);
        o1.z = pack2(f3.x, f3.y); o1.w = pack2(f3.z, f3.w);
        *(uint4*)(Wb + e)     = o0;
        *(uint4*)(Wb + e + 8) = o1;
    }
}

// ---------------------------------------------------------------------------
// GEMM core (m97 structure): 128x128 tile, BK=64, 4 waves, LDS linear [128][64]
// bf16 (16 KB/tile), staged via 8x global_load_lds_dwordx4 per wave per K-step.
// Each wave stages rows [wave*32, wave*32+32): chunk i = 8 rows = 1 KB.
// ---------------------------------------------------------------------------
#define GEMM_STAGE_AND_MMA(Ag, Bg)                                             \
    for (int k0 = 0; k0 < K; k0 += 64) {                                       \
        __syncthreads();                                                       \
        _Pragma("unroll")                                                      \
        for (int i = 0; i < 4; ++i) {                                          \
            async16(Ag + (size_t)i * 8 * K + k0, Al + i * 512);                \
            async16(Bg + (size_t)i * 8 * K + k0, Bl + i * 512);                \
        }                                                                      \
        __syncthreads();                                                       \
        _Pragma("unroll")                                                      \
        for (int ki = 0; ki < 2; ++ki) {                                       \
            const int kx = ki * 32 + quad * 8;                                 \
            short8 af[4], bf[4];                                               \
            _Pragma("unroll")                                                  \
            for (int s = 0; s < 4; ++s)                                        \
                af[s] = *(const short8*)&As[a_base + s * 16 * 64 + kx];        \
            _Pragma("unroll")                                                  \
            for (int s = 0; s < 4; ++s)                                        \
                bf[s] = *(const short8*)&Bs[b_base + s * 16 * 64 + kx];        \
            _Pragma("unroll")                                                  \
            for (int a = 0; a < 4; ++a)                                        \
                _Pragma("unroll")                                              \
                for (int b = 0; b < 4; ++b)                                    \
                    acc[a][b] = __builtin_amdgcn_mfma_f32_16x16x32_bf16(       \
                        af[a], bf[b], acc[a][b], 0, 0, 0);                     \
        }                                                                      \
    }

// K1b: out[0:pivot] = tanh(Xb @ Wb^T + b)
__global__ __launch_bounds__(256) void k1b_gemm_tanh(
    const short* __restrict__ A,      // Xb  (pivot x 1024 bf16)
    const short* __restrict__ B,      // Wb  (1024 x 1024 bf16)
    const float* __restrict__ Bv,
    float* __restrict__ out, int K)
{
    __shared__ __align__(16) short As[128 * 64];
    __shared__ __align__(16) short Bs[128 * 64];

    const int tid  = threadIdx.x;
    const int lane = tid & 63;
    const int wave = tid >> 6;
    const int wm = wave & 1, wn = wave >> 1;

    int row0, col0;
    swizzle_tile(row0, col0);

    const int l15  = lane & 15;
    const int quad = lane >> 4;
    const int a_base = (wm * 64 + l15) * 64;
    const int b_base = (wn * 64 + l15) * 64;

    const int lrow = lane >> 3;          // row within 8-row chunk
    const int lcol = lane & 7;           // 16 B unit within row
    const short* Ag = A + (size_t)(row0 + wave * 32 + lrow) * K + lcol * 8;
    const short* Bg = B + (size_t)(col0 + wave * 32 + lrow) * K + lcol * 8;
    short* Al = As + wave * 32 * 64;     // wave-uniform LDS base
    short* Bl = Bs + wave * 32 * 64;

    floatx4 acc[4][4];
#pragma unroll
    for (int a = 0; a < 4; ++a)
#pragma unroll
        for (int b = 0; b < 4; ++b) acc[a][b] = (floatx4){0.f, 0.f, 0.f, 0.f};

    GEMM_STAGE_AND_MMA(Ag, Bg)

    float bv[4];
#pragma unroll
    for (int b = 0; b < 4; ++b)
        bv[b] = Bv[col0 + wn * 64 + b * 16 + l15];

#pragma unroll
    for (int a = 0; a < 4; ++a) {
        const int rbase = row0 + wm * 64 + a * 16 + quad * 4;
#pragma unroll
        for (int b = 0; b < 4; ++b) {
            const int n = col0 + wn * 64 + b * 16 + l15;
#pragma unroll
            for (int r = 0; r < 4; ++r)
                out[(size_t)(rbase + r) * 1024 + n] = tanh_fast(acc[a][b][r] + bv[b]);
        }
    }
}

// K2b: C2 = Mb @ Wb^T; out2[2p+(i>=512)][(2i+kk)%1024] = (1-h^2)*C2[2p+kk][i]
__global__ __launch_bounds__(256) void k2b_gemm_jac(
    const short* __restrict__ A,      // Mb  (2*pivot x 1024 bf16, de-interleaved)
    const short* __restrict__ B,      // Wb
    const float* __restrict__ Hout,   // hAx rows [0, pivot)
    float* __restrict__ out2, int K)
{
    __shared__ __align__(16) short As[128 * 64];
    __shared__ __align__(16) short Bs[128 * 64];

    const int tid  = threadIdx.x;
    const int lane = tid & 63;
    const int wave = tid >> 6;
    const int wm = wave & 1, wn = wave >> 1;

    int r0, col0;
    swizzle_tile(r0, col0);

    const int l15  = lane & 15;
    const int quad = lane >> 4;
    const int a_base = (wm * 64 + l15) * 64;
    const int b_base = (wn * 64 + l15) * 64;

    const int lrow = lane >> 3;
    const int lcol = lane & 7;
    const short* Ag = A + (size_t)(r0 + wave * 32 + lrow) * K + lcol * 8;
    const short* Bg = B + (size_t)(col0 + wave * 32 + lrow) * K + lcol * 8;
    short* Al = As + wave * 32 * 64;
    short* Bl = Bs + wave * 32 * 64;

    floatx4 acc[4][4];
#pragma unroll
    for (int a = 0; a < 4; ++a)
#pragma unroll
        for (int b = 0; b < 4; ++b) acc[a][b] = (floatx4){0.f, 0.f, 0.f, 0.f};

    GEMM_STAGE_AND_MMA(Ag, Bg)

    // epilogue: acc regs (0,1)/(2,3) are M-rows (2p, 2p+1) -> one float2 store
#pragma unroll
    for (int a = 0; a < 4; ++a) {
        const int rb = r0 + wm * 64 + a * 16 + quad * 4;   // even
#pragma unroll
        for (int b = 0; b < 4; ++b) {
            const int i = col0 + wn * 64 + b * 16 + l15;
            const int shift = (i >= 512) ? 1 : 0;
            const int ccol = 2 * i - shift * 1024;
#pragma unroll
            for (int pr = 0; pr < 2; ++pr) {
                const int re = rb + pr * 2;                // even row = 2p
                const int p  = re >> 1;
                const float h  = Hout[(size_t)p * 1024 + i];
                const float hp = 1.0f - h * h;
                float2 st;
                st.x = hp * acc[a][b][pr * 2];             // kk=0 -> col 2i
                st.y = hp * acc[a][b][pr * 2 + 1];         // kk=1 -> col 2i+1
                *(float2*)&out2[(size_t)(re + shift) * 1024 + ccol] = st;
            }
        }
    }
}

// ===========================================================================
// FALLBACK PATH (R3 kernels, harness-verified): f32 reg-staged, LDS pad 72
// ===========================================================================
#define LDS_STRIDE 72

__global__ __launch_bounds__(256) void k1_gemm_tanh(
    const float* __restrict__ X, const float* __restrict__ W,
    const float* __restrict__ Bv, float* __restrict__ out, int K)
{
    __shared__ __align__(16) short As[128 * LDS_STRIDE];
    __shared__ __align__(16) short Bs[128 * LDS_STRIDE];
    const int tid  = threadIdx.x;
    const int lane = tid & 63;
    const int wave = tid >> 6;
    const int wm = wave & 1, wn = wave >> 1;
    int row0, col0;
    swizzle_tile(row0, col0);
    const int l15  = lane & 15;
    const int quad = lane >> 4;
    const int a_base = (wm * 64 + l15) * LDS_STRIDE;
    const int b_base = (wn * 64 + l15) * LDS_STRIDE;

    floatx4 acc[4][4];
#pragma unroll
    for (int a = 0; a < 4; ++a)
#pragma unroll
        for (int b = 0; b < 4; ++b) acc[a][b] = (floatx4){0.f, 0.f, 0.f, 0.f};

    for (int k0 = 0; k0 < K; k0 += 64) {
        __syncthreads();
#pragma unroll
        for (int i = 0; i < 8; ++i) {
            const int g = i * 256 + tid;
            const int r = g >> 4, c = g & 15;
            const float4 va = *(const float4*)(X + (size_t)(row0 + r) * K + k0 + c * 4);
            const float4 vb = *(const float4*)(W + (size_t)(col0 + r) * K + k0 + c * 4);
            uint2 ea, eb;
            ea.x = pack2(va.x, va.y); ea.y = pack2(va.z, va.w);
            eb.x = pack2(vb.x, vb.y); eb.y = pack2(vb.z, vb.w);
            *(uint2*)&As[r * LDS_STRIDE + c * 4] = ea;
            *(uint2*)&Bs[r * LDS_STRIDE + c * 4] = eb;
        }
        __syncthreads();
#pragma unroll
        for (int ki = 0; ki < 2; ++ki) {
            const int kx = ki * 32 + quad * 8;
            short8 af[4], bf[4];
#pragma unroll
            for (int s = 0; s < 4; ++s)
                af[s] = *(const short8*)&As[a_base + s * 16 * LDS_STRIDE + kx];
#pragma unroll
            for (int s = 0; s < 4; ++s)
                bf[s] = *(const short8*)&Bs[b_base + s * 16 * LDS_STRIDE + kx];
#pragma unroll
            for (int a = 0; a < 4; ++a)
#pragma unroll
                for (int b = 0; b < 4; ++b)
                    acc[a][b] = __builtin_amdgcn_mfma_f32_16x16x32_bf16(
                        af[a], bf[b], acc[a][b], 0, 0, 0);
        }
    }

    float bv[4];
#pragma unroll
    for (int b = 0; b < 4; ++b)
        bv[b] = Bv[col0 + wn * 64 + b * 16 + l15];
#pragma unroll
    for (int a = 0; a < 4; ++a) {
        const int rbase = row0 + wm * 64 + a * 16 + quad * 4;
#pragma unroll
        for (int b = 0; b < 4; ++b) {
            const int n = col0 + wn * 64 + b * 16 + l15;
#pragma unroll
            for (int r = 0; r < 4; ++r)
                out[(size_t)(rbase + r) * 1024 + n] = tanh_fast(acc[a][b][r] + bv[b]);
        }
    }
}

__global__ __launch_bounds__(256) void k2_gemm_jac(
    const float* __restrict__ G, const float* __restrict__ W,
    const float* __restrict__ Hout, float* __restrict__ out2, int K)
{
    __shared__ __align__(16) short As[128 * LDS_STRIDE];
    __shared__ __align__(16) short Bs[128 * LDS_STRIDE];
    const int tid  = threadIdx.x;
    const int lane = tid & 63;
    const int wave = tid >> 6;
    const int wm = wave & 1, wn = wave >> 1;
    int r0, col0;
    swizzle_tile(r0, col0);
    const int p0 = r0 >> 1;
    const int l15  = lane & 15;
    const int quad = lane >> 4;
    const int a_base = (wm * 64 + l15) * LDS_STRIDE;
    const int b_base = (wn * 64 + l15) * LDS_STRIDE;

    floatx4 acc[4][4];
#pragma unroll
    for (int a = 0; a < 4; ++a)
#pragma unroll
        for (int b = 0; b < 4; ++b) acc[a][b] = (floatx4){0.f, 0.f, 0.f, 0.f};

    for (int k0 = 0; k0 < K; k0 += 64) {
        __syncthreads();
#pragma unroll
        for (int i = 0; i < 8; ++i) {
            const int g = i * 256 + tid;
            const int r = g >> 4, c = g & 15;
            const float4 vb = *(const float4*)(W + (size_t)(col0 + r) * K + k0 + c * 4);
            uint2 eb;
            eb.x = pack2(vb.x, vb.y); eb.y = pack2(vb.z, vb.w);
            *(uint2*)&Bs[r * LDS_STRIDE + c * 4] = eb;
        }
#pragma unroll
        for (int i = 0; i < 4; ++i) {
            const int g = i * 256 + tid;
            const int q = g >> 4, d = g & 15;
            const float* src = G + (size_t)(p0 + q) * 2048 + 2 * k0 + d * 8;
            const float4 u0 = *(const float4*)src;
            const float4 u1 = *(const float4*)(src + 4);
            uint2 E, O;
            E.x = pack2(u0.x, u0.z); E.y = pack2(u1.x, u1.z);
            O.x = pack2(u0.y, u0.w); O.y = pack2(u1.y, u1.w);
            *(uint2*)&As[(2 * q)     * LDS_STRIDE + d * 4] = E;
            *(uint2*)&As[(2 * q + 1) * LDS_STRIDE + d * 4] = O;
        }
        __syncthreads();
#pragma unroll
        for (int ki = 0; ki < 2; ++ki) {
            const int kx = ki * 32 + quad * 8;
            short8 af[4], bf[4];
#pragma unroll
            for (int s = 0; s < 4; ++s)
                af[s] = *(const short8*)&As[a_base + s * 16 * LDS_STRIDE + kx];
#pragma unroll
            for (int s = 0; s < 4; ++s)
                bf[s] = *(const short8*)&Bs[b_base + s * 16 * LDS_STRIDE + kx];
#pragma unroll
            for (int a = 0; a < 4; ++a)
#pragma unroll
                for (int b = 0; b < 4; ++b)
                    acc[a][b] = __builtin_amdgcn_mfma_f32_16x16x32_bf16(
                        af[a], bf[b], acc[a][b], 0, 0, 0);
        }
    }

#pragma unroll
    for (int a = 0; a < 4; ++a) {
        const int rb = r0 + wm * 64 + a * 16 + quad * 4;
#pragma unroll
        for (int b = 0; b < 4; ++b) {
            const int i = col0 + wn * 64 + b * 16 + l15;
            const int shift = (i >= 512) ? 1 : 0;
            const int ccol = 2 * i - shift * 1024;
#pragma unroll
            for (int pr = 0; pr < 2; ++pr) {
                const int re = rb + pr * 2;
                const int p  = re >> 1;
                const float h  = Hout[(size_t)p * 1024 + i];
                const float hp = 1.0f - h * h;
                float2 st;
                st.x = hp * acc[a][b][pr * 2];
                st.y = hp * acc[a][b][pr * 2 + 1];
                *(float2*)&out2[(size_t)(re + shift) * 1024 + ccol] = st;
            }
        }
    }
}

extern "C" void kernel_launch(void* const* d_in, const int* in_sizes, int n_in,
                              void* d_out, int out_size, void* d_ws, size_t ws_size,
                              hipStream_t stream) {
    const float* xJx = (const float*)d_in[0];
    const float* W   = (const float*)d_in[1];
    const float* bv  = (const float*)d_in[2];
    float* out = (float*)d_out;

    const int C     = 1024;
    const int rows3 = in_sizes[0] / C;   // 3*pivot
    const int pivot = rows3 / 3;         // 16384

    const size_t szXb = (size_t)pivot * C * 2;          // 32 MB
    const size_t szMb = (size_t)2 * pivot * C * 2;      // 64 MB
    const size_t szWb = (size_t)C * C * 2;              //  2 MB
    dim3 blk(256);

    if (ws_size >= szXb + szMb + szWb) {
        short* Xb = (short*)d_ws;
        short* Mb = (short*)((char*)d_ws + szXb);
        short* Wb = (short*)((char*)d_ws + szXb + szMb);

        const int nbX = (pivot * C) / 4096;             // 4096
        const int nbG = (pivot * 2 * C) / 4096;         // 8192
        const int nbW = (C * C) / 4096;                 //  256
        cvt_prep<<<dim3(nbX + nbG + nbW), blk, 0, stream>>>(
            xJx, xJx + (size_t)pivot * C, W, Xb, Mb, Wb, nbX, nbG);

        dim3 g1(C / 128, pivot / 128);                  // 8 x 128
        k1b_gemm_tanh<<<g1, blk, 0, stream>>>(Xb, Wb, bv, out, C);

        dim3 g2(C / 128, (2 * pivot) / 128);            // 8 x 256
        k2b_gemm_jac<<<g2, blk, 0, stream>>>(Mb, Wb, out,
                                             out + (size_t)pivot * C, C);
    } else {
        dim3 g1(C / 128, pivot / 128);
        k1_gemm_tanh<<<g1, blk, 0, stream>>>(xJx, W, bv, out, C);
        dim3 g2(C / 128, (2 * pivot) / 128);
        k2_gemm_jac<<<g2, blk, 0, stream>>>(xJx + (size_t)pivot * C, W, out,
                                            out + (size_t)pivot * C, C);
    }
}

// Round 5
// 508.504 us; speedup vs baseline: 1.4123x; 1.0231x over previous
//
#include <hip/hip_runtime.h>
#include <hip/hip_bf16.h>
#include <cstdint>

typedef __attribute__((ext_vector_type(8))) short short8;
typedef __attribute__((ext_vector_type(4))) float floatx4;

__device__ __forceinline__ float tanh_fast(float x) {
    float e = __expf(2.0f * x);                            // v_exp_f32 path
    return 1.0f - 2.0f * __builtin_amdgcn_rcpf(e + 1.0f);  // saturates to +-1
}

__device__ __forceinline__ unsigned int bf16_bits(float f) {
    __hip_bfloat16 h = __float2bfloat16(f);   // RNE
    return (unsigned int)*reinterpret_cast<unsigned short*>(&h);
}
__device__ __forceinline__ unsigned int pack2(float lo, float hi) {
    return bf16_bits(lo) | (bf16_bits(hi) << 16);
}

// async global->LDS, 16 B per lane. LDS dest is wave-uniform base + lane*16.
__device__ __forceinline__ void async16(const void* g, void* l) {
    __builtin_amdgcn_global_load_lds(
        (const __attribute__((address_space(1))) unsigned int*)g,
        (__attribute__((address_space(3))) unsigned int*)l, 16, 0, 0);
}

// XCD-aware bijective block swizzle (VALIDATED: k1 FETCH 78 MB ~ ideal, k2
// 565->165 MB). Requires nwg % 8 == 0, gridDim.x == 8.
__device__ __forceinline__ void swizzle_tile(int& row0, int& col0) {
    const int nwg  = gridDim.x * gridDim.y;
    const int flat = blockIdx.y * gridDim.x + blockIdx.x;
    const int swz  = (flat & 7) * (nwg >> 3) + (flat >> 3);
    col0 = (swz & 7) * 128;
    row0 = (swz >> 3) * 128;
}

// ===========================================================================
// FAST PATH (needs 98 MB workspace): bf16 pre-pass + m97-style GEMMs
// ===========================================================================

// ---------------------------------------------------------------------------
// cvt_prep: X(f32)->Xb(bf16); G(f32, interleaved)->Mb(bf16, de-interleaved
// M[2p+kk][j] = G[p][2j+kk]); W(f32)->Wb(bf16). 16 f32/thread.
// ---------------------------------------------------------------------------
__global__ __launch_bounds__(256) void cvt_prep(
    const float* __restrict__ X, const float* __restrict__ G,
    const float* __restrict__ W,
    short* __restrict__ Xb, short* __restrict__ Mb, short* __restrict__ Wb,
    int nbX, int nbG)
{
    const int tid = threadIdx.x;
    const int b   = blockIdx.x;
    if (b < nbX) {                       // ---- X straight convert
        const size_t e = ((size_t)b * 256 + tid) * 16;
        const float4 f0 = *(const float4*)(X + e);
        const float4 f1 = *(const float4*)(X + e + 4);
        const float4 f2 = *(const float4*)(X + e + 8);
        const float4 f3 = *(const float4*)(X + e + 12);
        uint4 o0, o1;
        o0.x = pack2(f0.x, f0.y); o0.y = pack2(f0.z, f0.w);
        o0.z = pack2(f1.x, f1.y); o0.w = pack2(f1.z, f1.w);
        o1.x = pack2(f2.x, f2.y); o1.y = pack2(f2.z, f2.w);
        o1.z = pack2(f3.x, f3.y); o1.w = pack2(f3.z, f3.w);
        *(uint4*)(Xb + e)     = o0;
        *(uint4*)(Xb + e + 8) = o1;
    } else if (b < nbX + nbG) {          // ---- G de-interleave
        const size_t s = (size_t)(b - nbX) * 256 + tid;  // 16-float segment
        const size_t p = s >> 7;                         // G row (pair-row)
        const int    c = (int)(s & 127);                 // segment in row
        const float* src = G + p * 2048 + (size_t)c * 16;
        const float4 f0 = *(const float4*)(src);         // [j0k0 j0k1 j1k0 j1k1]
        const float4 f1 = *(const float4*)(src + 4);
        const float4 f2 = *(const float4*)(src + 8);
        const float4 f3 = *(const float4*)(src + 12);
        uint4 E, O;
        E.x = pack2(f0.x, f0.z); E.y = pack2(f1.x, f1.z);
        E.z = pack2(f2.x, f2.z); E.w = pack2(f3.x, f3.z);
        O.x = pack2(f0.y, f0.w); O.y = pack2(f1.y, f1.w);
        O.z = pack2(f2.y, f2.w); O.w = pack2(f3.y, f3.w);
        *(uint4*)(Mb + (2 * p)     * 1024 + (size_t)c * 8) = E;   // kk=0
        *(uint4*)(Mb + (2 * p + 1) * 1024 + (size_t)c * 8) = O;   // kk=1
    } else {                             // ---- W straight convert
        const size_t e = ((size_t)(b - nbX - nbG) * 256 + tid) * 16;
        const float4 f0 = *(const float4*)(W + e);
        const float4 f1 = *(const float4*)(W + e + 4);
        const float4 f2 = *(const float4*)(W + e + 8);
        const float4 f3 = *(const float4*)(W + e + 12);
        uint4 o0, o1;
        o0.x = pack2(f0.x, f0.y); o0.y = pack2(f0.z, f0.w);
        o0.z = pack2(f1.x, f1.y); o0.w = pack2(f1.z, f1.w);
        o1.x = pack2(f2.x, f2.y); o1.y = pack2(f2.z, f2.w);
        o1.z = pack2(f3.x, f3.y); o1.w = pack2(f3.z, f3.w);
        *(uint4*)(Wb + e)     = o0;
        *(uint4*)(Wb + e + 8) = o1;
    }
}

// ---------------------------------------------------------------------------
// GEMM core (m97 structure + T2 XOR swizzle): 128x128 tile, BK=64, 4 waves,
// LDS linear [128][64] bf16, staged via global_load_lds_dwordx4.
//
// Bank-conflict fix (rule #21: both-sides-or-neither): rows are 128 B = all
// 32 banks, so bank index = 16B-slot within row. Linear layout put 16 lanes
// on the same slot (16-way, 25.2M conflict cycles measured R4). Fix: LDS dest
// stays linear; the per-lane GLOBAL source is pre-permuted so LDS slot s of
// row r holds global chunk s^(r&7); reads XOR the slot with (row&7). A wave
// then spreads 64 lanes over all 8 slots -> serviced at the 8-clock wave64
// floor (conflict-free).
// ---------------------------------------------------------------------------
#define GEMM_STAGE_AND_MMA(Ag, Bg)                                             \
    for (int k0 = 0; k0 < K; k0 += 64) {                                       \
        __syncthreads();                                                       \
        _Pragma("unroll")                                                      \
        for (int i = 0; i < 4; ++i) {                                          \
            async16(Ag + (size_t)i * 8 * K + k0, Al + i * 512);                \
            async16(Bg + (size_t)i * 8 * K + k0, Bl + i * 512);                \
        }                                                                      \
        __syncthreads();                                                       \
        _Pragma("unroll")                                                      \
        for (int ki = 0; ki < 2; ++ki) {                                       \
            const int kxs = (((ki * 4 + quad) ^ rxor)) * 8;                    \
            short8 af[4], bf[4];                                               \
            _Pragma("unroll")                                                  \
            for (int s = 0; s < 4; ++s)                                        \
                af[s] = *(const short8*)&As[a_base + s * 16 * 64 + kxs];       \
            _Pragma("unroll")                                                  \
            for (int s = 0; s < 4; ++s)                                        \
                bf[s] = *(const short8*)&Bs[b_base + s * 16 * 64 + kxs];       \
            _Pragma("unroll")                                                  \
            for (int a = 0; a < 4; ++a)                                        \
                _Pragma("unroll")                                              \
                for (int b = 0; b < 4; ++b)                                    \
                    acc[a][b] = __builtin_amdgcn_mfma_f32_16x16x32_bf16(       \
                        af[a], bf[b], acc[a][b], 0, 0, 0);                     \
        }                                                                      \
    }

// K1b: out[0:pivot] = tanh(Xb @ Wb^T + b)
__global__ __launch_bounds__(256) void k1b_gemm_tanh(
    const short* __restrict__ A,      // Xb  (pivot x 1024 bf16)
    const short* __restrict__ B,      // Wb  (1024 x 1024 bf16)
    const float* __restrict__ Bv,
    float* __restrict__ out, int K)
{
    __shared__ __align__(16) short As[128 * 64];
    __shared__ __align__(16) short Bs[128 * 64];

    const int tid  = threadIdx.x;
    const int lane = tid & 63;
    const int wave = tid >> 6;
    const int wm = wave & 1, wn = wave >> 1;

    int row0, col0;
    swizzle_tile(row0, col0);

    const int l15  = lane & 15;
    const int quad = lane >> 4;
    const int rxor = l15 & 7;            // row&7 for all fragment rows
    const int a_base = (wm * 64 + l15) * 64;
    const int b_base = (wn * 64 + l15) * 64;

    const int lrow = lane >> 3;          // row within 8-row chunk
    const int lcol = lane & 7;           // 16 B unit within row
    const int cswz = lcol ^ lrow;        // pre-swizzled global chunk (T2)
    const short* Ag = A + (size_t)(row0 + wave * 32 + lrow) * K + cswz * 8;
    const short* Bg = B + (size_t)(col0 + wave * 32 + lrow) * K + cswz * 8;
    short* Al = As + wave * 32 * 64;     // wave-uniform LDS base
    short* Bl = Bs + wave * 32 * 64;

    floatx4 acc[4][4];
#pragma unroll
    for (int a = 0; a < 4; ++a)
#pragma unroll
        for (int b = 0; b < 4; ++b) acc[a][b] = (floatx4){0.f, 0.f, 0.f, 0.f};

    GEMM_STAGE_AND_MMA(Ag, Bg)

    float bv[4];
#pragma unroll
    for (int b = 0; b < 4; ++b)
        bv[b] = Bv[col0 + wn * 64 + b * 16 + l15];

#pragma unroll
    for (int a = 0; a < 4; ++a) {
        const int rbase = row0 + wm * 64 + a * 16 + quad * 4;
#pragma unroll
        for (int b = 0; b < 4; ++b) {
            const int n = col0 + wn * 64 + b * 16 + l15;
#pragma unroll
            for (int r = 0; r < 4; ++r)
                out[(size_t)(rbase + r) * 1024 + n] = tanh_fast(acc[a][b][r] + bv[b]);
        }
    }
}

// K2b: C2 = Mb @ Wb^T; out2[2p+(i>=512)][(2i+kk)%1024] = (1-h^2)*C2[2p+kk][i]
__global__ __launch_bounds__(256) void k2b_gemm_jac(
    const short* __restrict__ A,      // Mb  (2*pivot x 1024 bf16, de-interleaved)
    const short* __restrict__ B,      // Wb
    const float* __restrict__ Hout,   // hAx rows [0, pivot)
    float* __restrict__ out2, int K)
{
    __shared__ __align__(16) short As[128 * 64];
    __shared__ __align__(16) short Bs[128 * 64];

    const int tid  = threadIdx.x;
    const int lane = tid & 63;
    const int wave = tid >> 6;
    const int wm = wave & 1, wn = wave >> 1;

    int r0, col0;
    swizzle_tile(r0, col0);

    const int l15  = lane & 15;
    const int quad = lane >> 4;
    const int rxor = l15 & 7;
    const int a_base = (wm * 64 + l15) * 64;
    const int b_base = (wn * 64 + l15) * 64;

    const int lrow = lane >> 3;
    const int lcol = lane & 7;
    const int cswz = lcol ^ lrow;        // pre-swizzled global chunk (T2)
    const short* Ag = A + (size_t)(r0 + wave * 32 + lrow) * K + cswz * 8;
    const short* Bg = B + (size_t)(col0 + wave * 32 + lrow) * K + cswz * 8;
    short* Al = As + wave * 32 * 64;
    short* Bl = Bs + wave * 32 * 64;

    floatx4 acc[4][4];
#pragma unroll
    for (int a = 0; a < 4; ++a)
#pragma unroll
        for (int b = 0; b < 4; ++b) acc[a][b] = (floatx4){0.f, 0.f, 0.f, 0.f};

    GEMM_STAGE_AND_MMA(Ag, Bg)

    // epilogue: acc regs (0,1)/(2,3) are M-rows (2p, 2p+1) -> one float2 store
#pragma unroll
    for (int a = 0; a < 4; ++a) {
        const int rb = r0 + wm * 64 + a * 16 + quad * 4;   // even
#pragma unroll
        for (int b = 0; b < 4; ++b) {
            const int i = col0 + wn * 64 + b * 16 + l15;
            const int shift = (i >= 512) ? 1 : 0;
            const int ccol = 2 * i - shift * 1024;
#pragma unroll
            for (int pr = 0; pr < 2; ++pr) {
                const int re = rb + pr * 2;                // even row = 2p
                const int p  = re >> 1;
                const float h  = Hout[(size_t)p * 1024 + i];
                const float hp = 1.0f - h * h;
                float2 st;
                st.x = hp * acc[a][b][pr * 2];             // kk=0 -> col 2i
                st.y = hp * acc[a][b][pr * 2 + 1];         // kk=1 -> col 2i+1
                *(float2*)&out2[(size_t)(re + shift) * 1024 + ccol] = st;
            }
        }
    }
}

// ===========================================================================
// FALLBACK PATH (R3 kernels, harness-verified): f32 reg-staged, LDS pad 72
// ===========================================================================
#define LDS_STRIDE 72

__global__ __launch_bounds__(256) void k1_gemm_tanh(
    const float* __restrict__ X, const float* __restrict__ W,
    const float* __restrict__ Bv, float* __restrict__ out, int K)
{
    __shared__ __align__(16) short As[128 * LDS_STRIDE];
    __shared__ __align__(16) short Bs[128 * LDS_STRIDE];
    const int tid  = threadIdx.x;
    const int lane = tid & 63;
    const int wave = tid >> 6;
    const int wm = wave & 1, wn = wave >> 1;
    int row0, col0;
    swizzle_tile(row0, col0);
    const int l15  = lane & 15;
    const int quad = lane >> 4;
    const int a_base = (wm * 64 + l15) * LDS_STRIDE;
    const int b_base = (wn * 64 + l15) * LDS_STRIDE;

    floatx4 acc[4][4];
#pragma unroll
    for (int a = 0; a < 4; ++a)
#pragma unroll
        for (int b = 0; b < 4; ++b) acc[a][b] = (floatx4){0.f, 0.f, 0.f, 0.f};

    for (int k0 = 0; k0 < K; k0 += 64) {
        __syncthreads();
#pragma unroll
        for (int i = 0; i < 8; ++i) {
            const int g = i * 256 + tid;
            const int r = g >> 4, c = g & 15;
            const float4 va = *(const float4*)(X + (size_t)(row0 + r) * K + k0 + c * 4);
            const float4 vb = *(const float4*)(W + (size_t)(col0 + r) * K + k0 + c * 4);
            uint2 ea, eb;
            ea.x = pack2(va.x, va.y); ea.y = pack2(va.z, va.w);
            eb.x = pack2(vb.x, vb.y); eb.y = pack2(vb.z, vb.w);
            *(uint2*)&As[r * LDS_STRIDE + c * 4] = ea;
            *(uint2*)&Bs[r * LDS_STRIDE + c * 4] = eb;
        }
        __syncthreads();
#pragma unroll
        for (int ki = 0; ki < 2; ++ki) {
            const int kx = ki * 32 + quad * 8;
            short8 af[4], bf[4];
#pragma unroll
            for (int s = 0; s < 4; ++s)
                af[s] = *(const short8*)&As[a_base + s * 16 * LDS_STRIDE + kx];
#pragma unroll
            for (int s = 0; s < 4; ++s)
                bf[s] = *(const short8*)&Bs[b_base + s * 16 * LDS_STRIDE + kx];
#pragma unroll
            for (int a = 0; a < 4; ++a)
#pragma unroll
                for (int b = 0; b < 4; ++b)
                    acc[a][b] = __builtin_amdgcn_mfma_f32_16x16x32_bf16(
                        af[a], bf[b], acc[a][b], 0, 0, 0);
        }
    }

    float bv[4];
#pragma unroll
    for (int b = 0; b < 4; ++b)
        bv[b] = Bv[col0 + wn * 64 + b * 16 + l15];
#pragma unroll
    for (int a = 0; a < 4; ++a) {
        const int rbase = row0 + wm * 64 + a * 16 + quad * 4;
#pragma unroll
        for (int b = 0; b < 4; ++b) {
            const int n = col0 + wn * 64 + b * 16 + l15;
#pragma unroll
            for (int r = 0; r < 4; ++r)
                out[(size_t)(rbase + r) * 1024 + n] = tanh_fast(acc[a][b][r] + bv[b]);
        }
    }
}

__global__ __launch_bounds__(256) void k2_gemm_jac(
    const float* __restrict__ G, const float* __restrict__ W,
    const float* __restrict__ Hout, float* __restrict__ out2, int K)
{
    __shared__ __align__(16) short As[128 * LDS_STRIDE];
    __shared__ __align__(16) short Bs[128 * LDS_STRIDE];
    const int tid  = threadIdx.x;
    const int lane = tid & 63;
    const int wave = tid >> 6;
    const int wm = wave & 1, wn = wave >> 1;
    int r0, col0;
    swizzle_tile(r0, col0);
    const int p0 = r0 >> 1;
    const int l15  = lane & 15;
    const int quad = lane >> 4;
    const int a_base = (wm * 64 + l15) * LDS_STRIDE;
    const int b_base = (wn * 64 + l15) * LDS_STRIDE;

    floatx4 acc[4][4];
#pragma unroll
    for (int a = 0; a < 4; ++a)
#pragma unroll
        for (int b = 0; b < 4; ++b) acc[a][b] = (floatx4){0.f, 0.f, 0.f, 0.f};

    for (int k0 = 0; k0 < K; k0 += 64) {
        __syncthreads();
#pragma unroll
        for (int i = 0; i < 8; ++i) {
            const int g = i * 256 + tid;
            const int r = g >> 4, c = g & 15;
            const float4 vb = *(const float4*)(W + (size_t)(col0 + r) * K + k0 + c * 4);
            uint2 eb;
            eb.x = pack2(vb.x, vb.y); eb.y = pack2(vb.z, vb.w);
            *(uint2*)&Bs[r * LDS_STRIDE + c * 4] = eb;
        }
#pragma unroll
        for (int i = 0; i < 4; ++i) {
            const int g = i * 256 + tid;
            const int q = g >> 4, d = g & 15;
            const float* src = G + (size_t)(p0 + q) * 2048 + 2 * k0 + d * 8;
            const float4 u0 = *(const float4*)src;
            const float4 u1 = *(const float4*)(src + 4);
            uint2 E, O;
            E.x = pack2(u0.x, u0.z); E.y = pack2(u1.x, u1.z);
            O.x = pack2(u0.y, u0.w); O.y = pack2(u1.y, u1.w);
            *(uint2*)&As[(2 * q)     * LDS_STRIDE + d * 4] = E;
            *(uint2*)&As[(2 * q + 1) * LDS_STRIDE + d * 4] = O;
        }
        __syncthreads();
#pragma unroll
        for (int ki = 0; ki < 2; ++ki) {
            const int kx = ki * 32 + quad * 8;
            short8 af[4], bf[4];
#pragma unroll
            for (int s = 0; s < 4; ++s)
                af[s] = *(const short8*)&As[a_base + s * 16 * LDS_STRIDE + kx];
#pragma unroll
            for (int s = 0; s < 4; ++s)
                bf[s] = *(const short8*)&Bs[b_base + s * 16 * LDS_STRIDE + kx];
#pragma unroll
            for (int a = 0; a < 4; ++a)
#pragma unroll
                for (int b = 0; b < 4; ++b)
                    acc[a][b] = __builtin_amdgcn_mfma_f32_16x16x32_bf16(
                        af[a], bf[b], acc[a][b], 0, 0, 0);
        }
    }

#pragma unroll
    for (int a = 0; a < 4; ++a) {
        const int rb = r0 + wm * 64 + a * 16 + quad * 4;
#pragma unroll
        for (int b = 0; b < 4; ++b) {
            const int i = col0 + wn * 64 + b * 16 + l15;
            const int shift = (i >= 512) ? 1 : 0;
            const int ccol = 2 * i - shift * 1024;
#pragma unroll
            for (int pr = 0; pr < 2; ++pr) {
                const int re = rb + pr * 2;
                const int p  = re >> 1;
                const float h  = Hout[(size_t)p * 1024 + i];
                const float hp = 1.0f - h * h;
                float2 st;
                st.x = hp * acc[a][b][pr * 2];
                st.y = hp * acc[a][b][pr * 2 + 1];
                *(float2*)&out2[(size_t)(re + shift) * 1024 + ccol] = st;
            }
        }
    }
}

extern "C" void kernel_launch(void* const* d_in, const int* in_sizes, int n_in,
                              void* d_out, int out_size, void* d_ws, size_t ws_size,
                              hipStream_t stream) {
    const float* xJx = (const float*)d_in[0];
    const float* W   = (const float*)d_in[1];
    const float* bv  = (const float*)d_in[2];
    float* out = (float*)d_out;

    const int C     = 1024;
    const int rows3 = in_sizes[0] / C;   // 3*pivot
    const int pivot = rows3 / 3;         // 16384

    const size_t szXb = (size_t)pivot * C * 2;          // 32 MB
    const size_t szMb = (size_t)2 * pivot * C * 2;      // 64 MB
    const size_t szWb = (size_t)C * C * 2;              //  2 MB
    dim3 blk(256);

    if (ws_size >= szXb + szMb + szWb) {
        short* Xb = (short*)d_ws;
        short* Mb = (short*)((char*)d_ws + szXb);
        short* Wb = (short*)((char*)d_ws + szXb + szMb);

        const int nbX = (pivot * C) / 4096;             // 4096
        const int nbG = (pivot * 2 * C) / 4096;         // 8192
        const int nbW = (C * C) / 4096;                 //  256
        cvt_prep<<<dim3(nbX + nbG + nbW), blk, 0, stream>>>(
            xJx, xJx + (size_t)pivot * C, W, Xb, Mb, Wb, nbX, nbG);

        dim3 g1(C / 128, pivot / 128);                  // 8 x 128
        k1b_gemm_tanh<<<g1, blk, 0, stream>>>(Xb, Wb, bv, out, C);

        dim3 g2(C / 128, (2 * pivot) / 128);            // 8 x 256
        k2b_gemm_jac<<<g2, blk, 0, stream>>>(Mb, Wb, out,
                                             out + (size_t)pivot * C, C);
    } else {
        dim3 g1(C / 128, pivot / 128);
        k1_gemm_tanh<<<g1, blk, 0, stream>>>(xJx, W, bv, out, C);
        dim3 g2(C / 128, (2 * pivot) / 128);
        k2_gemm_jac<<<g2, blk, 0, stream>>>(xJx + (size_t)pivot * C, W, out,
                                            out + (size_t)pivot * C, C);
    }
}

// Round 6
// 503.465 us; speedup vs baseline: 1.4264x; 1.0100x over previous
//
#include <hip/hip_runtime.h>
#include <hip/hip_bf16.h>
#include <cstdint>

typedef __attribute__((ext_vector_type(8))) short short8;
typedef __attribute__((ext_vector_type(4))) float floatx4;

__device__ __forceinline__ float tanh_fast(float x) {
    float e = __expf(2.0f * x);                            // v_exp_f32 path
    return 1.0f - 2.0f * __builtin_amdgcn_rcpf(e + 1.0f);  // saturates to +-1
}

__device__ __forceinline__ unsigned int bf16_bits(float f) {
    __hip_bfloat16 h = __float2bfloat16(f);   // RNE
    return (unsigned int)*reinterpret_cast<unsigned short*>(&h);
}
__device__ __forceinline__ unsigned int pack2(float lo, float hi) {
    return bf16_bits(lo) | (bf16_bits(hi) << 16);
}

// async global->LDS, 16 B per lane. LDS dest is wave-uniform base + lane*16.
__device__ __forceinline__ void async16(const void* g, void* l) {
    __builtin_amdgcn_global_load_lds(
        (const __attribute__((address_space(1))) unsigned int*)g,
        (__attribute__((address_space(3))) unsigned int*)l, 16, 0, 0);
}

// XCD-aware bijective block swizzle (VALIDATED: k1 FETCH 78 MB ~ ideal, k2
// 565->165 MB). Requires nwg % 8 == 0, gridDim.x == 8.
__device__ __forceinline__ void swizzle_tile(int& row0, int& col0) {
    const int nwg  = gridDim.x * gridDim.y;
    const int flat = blockIdx.y * gridDim.x + blockIdx.x;
    const int swz  = (flat & 7) * (nwg >> 3) + (flat >> 3);
    col0 = (swz & 7) * 128;
    row0 = (swz >> 3) * 128;
}

// ===========================================================================
// FAST PATH (needs 98 MB workspace): bf16 pre-pass + pipelined GEMMs
// ===========================================================================

// ---------------------------------------------------------------------------
// cvt_prep: X(f32)->Xb(bf16); G(f32, interleaved)->Mb(bf16, de-interleaved
// M[2p+kk][j] = G[p][2j+kk]); W(f32)->Wb(bf16). 16 f32/thread.
// ---------------------------------------------------------------------------
__global__ __launch_bounds__(256) void cvt_prep(
    const float* __restrict__ X, const float* __restrict__ G,
    const float* __restrict__ W,
    short* __restrict__ Xb, short* __restrict__ Mb, short* __restrict__ Wb,
    int nbX, int nbG)
{
    const int tid = threadIdx.x;
    const int b   = blockIdx.x;
    if (b < nbX) {                       // ---- X straight convert
        const size_t e = ((size_t)b * 256 + tid) * 16;
        const float4 f0 = *(const float4*)(X + e);
        const float4 f1 = *(const float4*)(X + e + 4);
        const float4 f2 = *(const float4*)(X + e + 8);
        const float4 f3 = *(const float4*)(X + e + 12);
        uint4 o0, o1;
        o0.x = pack2(f0.x, f0.y); o0.y = pack2(f0.z, f0.w);
        o0.z = pack2(f1.x, f1.y); o0.w = pack2(f1.z, f1.w);
        o1.x = pack2(f2.x, f2.y); o1.y = pack2(f2.z, f2.w);
        o1.z = pack2(f3.x, f3.y); o1.w = pack2(f3.z, f3.w);
        *(uint4*)(Xb + e)     = o0;
        *(uint4*)(Xb + e + 8) = o1;
    } else if (b < nbX + nbG) {          // ---- G de-interleave
        const size_t s = (size_t)(b - nbX) * 256 + tid;  // 16-float segment
        const size_t p = s >> 7;                         // G row (pair-row)
        const int    c = (int)(s & 127);                 // segment in row
        const float* src = G + p * 2048 + (size_t)c * 16;
        const float4 f0 = *(const float4*)(src);         // [j0k0 j0k1 j1k0 j1k1]
        const float4 f1 = *(const float4*)(src + 4);
        const float4 f2 = *(const float4*)(src + 8);
        const float4 f3 = *(const float4*)(src + 12);
        uint4 E, O;
        E.x = pack2(f0.x, f0.z); E.y = pack2(f1.x, f1.z);
        E.z = pack2(f2.x, f2.z); E.w = pack2(f3.x, f3.z);
        O.x = pack2(f0.y, f0.w); O.y = pack2(f1.y, f1.w);
        O.z = pack2(f2.y, f2.w); O.w = pack2(f3.y, f3.w);
        *(uint4*)(Mb + (2 * p)     * 1024 + (size_t)c * 8) = E;   // kk=0
        *(uint4*)(Mb + (2 * p + 1) * 1024 + (size_t)c * 8) = O;   // kk=1
    } else {                             // ---- W straight convert
        const size_t e = ((size_t)(b - nbX - nbG) * 256 + tid) * 16;
        const float4 f0 = *(const float4*)(W + e);
        const float4 f1 = *(const float4*)(W + e + 4);
        const float4 f2 = *(const float4*)(W + e + 8);
        const float4 f3 = *(const float4*)(W + e + 12);
        uint4 o0, o1;
        o0.x = pack2(f0.x, f0.y); o0.y = pack2(f0.z, f0.w);
        o0.z = pack2(f1.x, f1.y); o0.w = pack2(f1.z, f1.w);
        o1.x = pack2(f2.x, f2.y); o1.y = pack2(f2.z, f2.w);
        o1.z = pack2(f3.x, f3.y); o1.w = pack2(f3.z, f3.w);
        *(uint4*)(Wb + e)     = o0;
        *(uint4*)(Wb + e + 8) = o1;
    }
}

// ---------------------------------------------------------------------------
// GEMM core: 128x128 tile, BK=64, 4 waves, DOUBLE-BUFFERED linear LDS
// [2][128][64] bf16 staged via global_load_lds_dwordx4 (T3-minimum 2-phase).
//
// Schedule per K-step: issue next tile's async loads into buf^1 FIRST, then
// ds_read+MFMA on buf, then ONE __syncthreads() (its implicit vmcnt(0) drain
// lands after ~300 cyc of compute -> load latency hidden). R5's structure
// exposed the full load latency between two barriers every K-step (MfmaUtil
// 21%, all pipes <30%).
//
// Bank-conflict fix (VALIDATED R5: 25.2M -> 0): LDS dest linear; per-lane
// GLOBAL source pre-permuted so LDS slot s of row r holds chunk s^(r&7);
// fragment reads XOR the slot with (row&7).
// ---------------------------------------------------------------------------
#define GEMM_PIPELINED(Ag, Bg)                                                 \
    {                                                                          \
        const int nt = K >> 6;                                                 \
        _Pragma("unroll")                                                      \
        for (int i = 0; i < 4; ++i) {                                          \
            async16(Ag + (size_t)i * 8 * K, As + wave * 2048 + i * 512);       \
            async16(Bg + (size_t)i * 8 * K, Bs + wave * 2048 + i * 512);       \
        }                                                                      \
        __syncthreads();                                                       \
        for (int t = 0; t < nt; ++t) {                                         \
            const short* Asc = As + (t & 1) * 8192;                            \
            const short* Bsc = Bs + (t & 1) * 8192;                            \
            if (t + 1 < nt) {                                                  \
                short* Asn = As + ((t + 1) & 1) * 8192;                        \
                short* Bsn = Bs + ((t + 1) & 1) * 8192;                        \
                const int kn = (t + 1) * 64;                                   \
                _Pragma("unroll")                                              \
                for (int i = 0; i < 4; ++i) {                                  \
                    async16(Ag + (size_t)i * 8 * K + kn,                       \
                            Asn + wave * 2048 + i * 512);                      \
                    async16(Bg + (size_t)i * 8 * K + kn,                       \
                            Bsn + wave * 2048 + i * 512);                      \
                }                                                              \
            }                                                                  \
            _Pragma("unroll")                                                  \
            for (int ki = 0; ki < 2; ++ki) {                                   \
                const int kxs = ((ki * 4 + quad) ^ rxor) * 8;                  \
                short8 af[4], bf[4];                                           \
                _Pragma("unroll")                                              \
                for (int s = 0; s < 4; ++s)                                    \
                    af[s] = *(const short8*)&Asc[a_base + s * 1024 + kxs];     \
                _Pragma("unroll")                                              \
                for (int s = 0; s < 4; ++s)                                    \
                    bf[s] = *(const short8*)&Bsc[b_base + s * 1024 + kxs];     \
                _Pragma("unroll")                                              \
                for (int a = 0; a < 4; ++a)                                    \
                    _Pragma("unroll")                                          \
                    for (int b = 0; b < 4; ++b)                                \
                        acc[a][b] = __builtin_amdgcn_mfma_f32_16x16x32_bf16(   \
                            af[a], bf[b], acc[a][b], 0, 0, 0);                 \
            }                                                                  \
            __syncthreads();                                                   \
        }                                                                      \
    }

// K1b: out[0:pivot] = tanh(Xb @ Wb^T + b)
__global__ __launch_bounds__(256) void k1b_gemm_tanh(
    const short* __restrict__ A,      // Xb  (pivot x 1024 bf16)
    const short* __restrict__ B,      // Wb  (1024 x 1024 bf16)
    const float* __restrict__ Bv,
    float* __restrict__ out, int K)
{
    __shared__ __align__(16) short As[2 * 128 * 64];
    __shared__ __align__(16) short Bs[2 * 128 * 64];

    const int tid  = threadIdx.x;
    const int lane = tid & 63;
    const int wave = tid >> 6;
    const int wm = wave & 1, wn = wave >> 1;

    int row0, col0;
    swizzle_tile(row0, col0);

    const int l15  = lane & 15;
    const int quad = lane >> 4;
    const int rxor = l15 & 7;            // row&7 for all fragment rows
    const int a_base = (wm * 64 + l15) * 64;
    const int b_base = (wn * 64 + l15) * 64;

    const int lrow = lane >> 3;          // row within 8-row chunk
    const int lcol = lane & 7;           // 16 B unit within row
    const int cswz = lcol ^ lrow;        // pre-swizzled global chunk (T2)
    const short* Ag = A + (size_t)(row0 + wave * 32 + lrow) * K + cswz * 8;
    const short* Bg = B + (size_t)(col0 + wave * 32 + lrow) * K + cswz * 8;

    floatx4 acc[4][4];
#pragma unroll
    for (int a = 0; a < 4; ++a)
#pragma unroll
        for (int b = 0; b < 4; ++b) acc[a][b] = (floatx4){0.f, 0.f, 0.f, 0.f};

    GEMM_PIPELINED(Ag, Bg)

    float bv[4];
#pragma unroll
    for (int b = 0; b < 4; ++b)
        bv[b] = Bv[col0 + wn * 64 + b * 16 + l15];

#pragma unroll
    for (int a = 0; a < 4; ++a) {
        const int rbase = row0 + wm * 64 + a * 16 + quad * 4;
#pragma unroll
        for (int b = 0; b < 4; ++b) {
            const int n = col0 + wn * 64 + b * 16 + l15;
#pragma unroll
            for (int r = 0; r < 4; ++r)
                out[(size_t)(rbase + r) * 1024 + n] = tanh_fast(acc[a][b][r] + bv[b]);
        }
    }
}

// K2b: C2 = Mb @ Wb^T; out2[2p+(i>=512)][(2i+kk)%1024] = (1-h^2)*C2[2p+kk][i]
__global__ __launch_bounds__(256) void k2b_gemm_jac(
    const short* __restrict__ A,      // Mb  (2*pivot x 1024 bf16, de-interleaved)
    const short* __restrict__ B,      // Wb
    const float* __restrict__ Hout,   // hAx rows [0, pivot)
    float* __restrict__ out2, int K)
{
    __shared__ __align__(16) short As[2 * 128 * 64];
    __shared__ __align__(16) short Bs[2 * 128 * 64];

    const int tid  = threadIdx.x;
    const int lane = tid & 63;
    const int wave = tid >> 6;
    const int wm = wave & 1, wn = wave >> 1;

    int r0, col0;
    swizzle_tile(r0, col0);

    const int l15  = lane & 15;
    const int quad = lane >> 4;
    const int rxor = l15 & 7;
    const int a_base = (wm * 64 + l15) * 64;
    const int b_base = (wn * 64 + l15) * 64;

    const int lrow = lane >> 3;
    const int lcol = lane & 7;
    const int cswz = lcol ^ lrow;        // pre-swizzled global chunk (T2)
    const short* Ag = A + (size_t)(r0 + wave * 32 + lrow) * K + cswz * 8;
    const short* Bg = B + (size_t)(col0 + wave * 32 + lrow) * K + cswz * 8;

    floatx4 acc[4][4];
#pragma unroll
    for (int a = 0; a < 4; ++a)
#pragma unroll
        for (int b = 0; b < 4; ++b) acc[a][b] = (floatx4){0.f, 0.f, 0.f, 0.f};

    GEMM_PIPELINED(Ag, Bg)

    // epilogue: acc regs (0,1)/(2,3) are M-rows (2p, 2p+1) -> one float2 store
#pragma unroll
    for (int a = 0; a < 4; ++a) {
        const int rb = r0 + wm * 64 + a * 16 + quad * 4;   // even
#pragma unroll
        for (int b = 0; b < 4; ++b) {
            const int i = col0 + wn * 64 + b * 16 + l15;
            const int shift = (i >= 512) ? 1 : 0;
            const int ccol = 2 * i - shift * 1024;
#pragma unroll
            for (int pr = 0; pr < 2; ++pr) {
                const int re = rb + pr * 2;                // even row = 2p
                const int p  = re >> 1;
                const float h  = Hout[(size_t)p * 1024 + i];
                const float hp = 1.0f - h * h;
                float2 st;
                st.x = hp * acc[a][b][pr * 2];             // kk=0 -> col 2i
                st.y = hp * acc[a][b][pr * 2 + 1];         // kk=1 -> col 2i+1
                *(float2*)&out2[(size_t)(re + shift) * 1024 + ccol] = st;
            }
        }
    }
}

// ===========================================================================
// FALLBACK PATH (R3 kernels, harness-verified): f32 reg-staged, LDS pad 72
// ===========================================================================
#define LDS_STRIDE 72

__global__ __launch_bounds__(256) void k1_gemm_tanh(
    const float* __restrict__ X, const float* __restrict__ W,
    const float* __restrict__ Bv, float* __restrict__ out, int K)
{
    __shared__ __align__(16) short As[128 * LDS_STRIDE];
    __shared__ __align__(16) short Bs[128 * LDS_STRIDE];
    const int tid  = threadIdx.x;
    const int lane = tid & 63;
    const int wave = tid >> 6;
    const int wm = wave & 1, wn = wave >> 1;
    int row0, col0;
    swizzle_tile(row0, col0);
    const int l15  = lane & 15;
    const int quad = lane >> 4;
    const int a_base = (wm * 64 + l15) * LDS_STRIDE;
    const int b_base = (wn * 64 + l15) * LDS_STRIDE;

    floatx4 acc[4][4];
#pragma unroll
    for (int a = 0; a < 4; ++a)
#pragma unroll
        for (int b = 0; b < 4; ++b) acc[a][b] = (floatx4){0.f, 0.f, 0.f, 0.f};

    for (int k0 = 0; k0 < K; k0 += 64) {
        __syncthreads();
#pragma unroll
        for (int i = 0; i < 8; ++i) {
            const int g = i * 256 + tid;
            const int r = g >> 4, c = g & 15;
            const float4 va = *(const float4*)(X + (size_t)(row0 + r) * K + k0 + c * 4);
            const float4 vb = *(const float4*)(W + (size_t)(col0 + r) * K + k0 + c * 4);
            uint2 ea, eb;
            ea.x = pack2(va.x, va.y); ea.y = pack2(va.z, va.w);
            eb.x = pack2(vb.x, vb.y); eb.y = pack2(vb.z, vb.w);
            *(uint2*)&As[r * LDS_STRIDE + c * 4] = ea;
            *(uint2*)&Bs[r * LDS_STRIDE + c * 4] = eb;
        }
        __syncthreads();
#pragma unroll
        for (int ki = 0; ki < 2; ++ki) {
            const int kx = ki * 32 + quad * 8;
            short8 af[4], bf[4];
#pragma unroll
            for (int s = 0; s < 4; ++s)
                af[s] = *(const short8*)&As[a_base + s * 16 * LDS_STRIDE + kx];
#pragma unroll
            for (int s = 0; s < 4; ++s)
                bf[s] = *(const short8*)&Bs[b_base + s * 16 * LDS_STRIDE + kx];
#pragma unroll
            for (int a = 0; a < 4; ++a)
#pragma unroll
                for (int b = 0; b < 4; ++b)
                    acc[a][b] = __builtin_amdgcn_mfma_f32_16x16x32_bf16(
                        af[a], bf[b], acc[a][b], 0, 0, 0);
        }
    }

    float bv[4];
#pragma unroll
    for (int b = 0; b < 4; ++b)
        bv[b] = Bv[col0 + wn * 64 + b * 16 + l15];
#pragma unroll
    for (int a = 0; a < 4; ++a) {
        const int rbase = row0 + wm * 64 + a * 16 + quad * 4;
#pragma unroll
        for (int b = 0; b < 4; ++b) {
            const int n = col0 + wn * 64 + b * 16 + l15;
#pragma unroll
            for (int r = 0; r < 4; ++r)
                out[(size_t)(rbase + r) * 1024 + n] = tanh_fast(acc[a][b][r] + bv[b]);
        }
    }
}

__global__ __launch_bounds__(256) void k2_gemm_jac(
    const float* __restrict__ G, const float* __restrict__ W,
    const float* __restrict__ Hout, float* __restrict__ out2, int K)
{
    __shared__ __align__(16) short As[128 * LDS_STRIDE];
    __shared__ __align__(16) short Bs[128 * LDS_STRIDE];
    const int tid  = threadIdx.x;
    const int lane = tid & 63;
    const int wave = tid >> 6;
    const int wm = wave & 1, wn = wave >> 1;
    int r0, col0;
    swizzle_tile(r0, col0);
    const int p0 = r0 >> 1;
    const int l15  = lane & 15;
    const int quad = lane >> 4;
    const int a_base = (wm * 64 + l15) * LDS_STRIDE;
    const int b_base = (wn * 64 + l15) * LDS_STRIDE;

    floatx4 acc[4][4];
#pragma unroll
    for (int a = 0; a < 4; ++a)
#pragma unroll
        for (int b = 0; b < 4; ++b) acc[a][b] = (floatx4){0.f, 0.f, 0.f, 0.f};

    for (int k0 = 0; k0 < K; k0 += 64) {
        __syncthreads();
#pragma unroll
        for (int i = 0; i < 8; ++i) {
            const int g = i * 256 + tid;
            const int r = g >> 4, c = g & 15;
            const float4 vb = *(const float4*)(W + (size_t)(col0 + r) * K + k0 + c * 4);
            uint2 eb;
            eb.x = pack2(vb.x, vb.y); eb.y = pack2(vb.z, vb.w);
            *(uint2*)&Bs[r * LDS_STRIDE + c * 4] = eb;
        }
#pragma unroll
        for (int i = 0; i < 4; ++i) {
            const int g = i * 256 + tid;
            const int q = g >> 4, d = g & 15;
            const float* src = G + (size_t)(p0 + q) * 2048 + 2 * k0 + d * 8;
            const float4 u0 = *(const float4*)src;
            const float4 u1 = *(const float4*)(src + 4);
            uint2 E, O;
            E.x = pack2(u0.x, u0.z); E.y = pack2(u1.x, u1.z);
            O.x = pack2(u0.y, u0.w); O.y = pack2(u1.y, u1.w);
            *(uint2*)&As[(2 * q)     * LDS_STRIDE + d * 4] = E;
            *(uint2*)&As[(2 * q + 1) * LDS_STRIDE + d * 4] = O;
        }
        __syncthreads();
#pragma unroll
        for (int ki = 0; ki < 2; ++ki) {
            const int kx = ki * 32 + quad * 8;
            short8 af[4], bf[4];
#pragma unroll
            for (int s = 0; s < 4; ++s)
                af[s] = *(const short8*)&As[a_base + s * 16 * LDS_STRIDE + kx];
#pragma unroll
            for (int s = 0; s < 4; ++s)
                bf[s] = *(const short8*)&Bs[b_base + s * 16 * LDS_STRIDE + kx];
#pragma unroll
            for (int a = 0; a < 4; ++a)
#pragma unroll
                for (int b = 0; b < 4; ++b)
                    acc[a][b] = __builtin_amdgcn_mfma_f32_16x16x32_bf16(
                        af[a], bf[b], acc[a][b], 0, 0, 0);
        }
    }

#pragma unroll
    for (int a = 0; a < 4; ++a) {
        const int rb = r0 + wm * 64 + a * 16 + quad * 4;
#pragma unroll
        for (int b = 0; b < 4; ++b) {
            const int i = col0 + wn * 64 + b * 16 + l15;
            const int shift = (i >= 512) ? 1 : 0;
            const int ccol = 2 * i - shift * 1024;
#pragma unroll
            for (int pr = 0; pr < 2; ++pr) {
                const int re = rb + pr * 2;
                const int p  = re >> 1;
                const float h  = Hout[(size_t)p * 1024 + i];
                const float hp = 1.0f - h * h;
                float2 st;
                st.x = hp * acc[a][b][pr * 2];
                st.y = hp * acc[a][b][pr * 2 + 1];
                *(float2*)&out2[(size_t)(re + shift) * 1024 + ccol] = st;
            }
        }
    }
}

extern "C" void kernel_launch(void* const* d_in, const int* in_sizes, int n_in,
                              void* d_out, int out_size, void* d_ws, size_t ws_size,
                              hipStream_t stream) {
    const float* xJx = (const float*)d_in[0];
    const float* W   = (const float*)d_in[1];
    const float* bv  = (const float*)d_in[2];
    float* out = (float*)d_out;

    const int C     = 1024;
    const int rows3 = in_sizes[0] / C;   // 3*pivot
    const int pivot = rows3 / 3;         // 16384

    const size_t szXb = (size_t)pivot * C * 2;          // 32 MB
    const size_t szMb = (size_t)2 * pivot * C * 2;      // 64 MB
    const size_t szWb = (size_t)C * C * 2;              //  2 MB
    dim3 blk(256);

    if (ws_size >= szXb + szMb + szWb) {
        short* Xb = (short*)d_ws;
        short* Mb = (short*)((char*)d_ws + szXb);
        short* Wb = (short*)((char*)d_ws + szXb + szMb);

        const int nbX = (pivot * C) / 4096;             // 4096
        const int nbG = (pivot * 2 * C) / 4096;         // 8192
        const int nbW = (C * C) / 4096;                 //  256
        cvt_prep<<<dim3(nbX + nbG + nbW), blk, 0, stream>>>(
            xJx, xJx + (size_t)pivot * C, W, Xb, Mb, Wb, nbX, nbG);

        dim3 g1(C / 128, pivot / 128);                  // 8 x 128
        k1b_gemm_tanh<<<g1, blk, 0, stream>>>(Xb, Wb, bv, out, C);

        dim3 g2(C / 128, (2 * pivot) / 128);            // 8 x 256
        k2b_gemm_jac<<<g2, blk, 0, stream>>>(Mb, Wb, out,
                                             out + (size_t)pivot * C, C);
    } else {
        dim3 g1(C / 128, pivot / 128);
        k1_gemm_tanh<<<g1, blk, 0, stream>>>(xJx, W, bv, out, C);
        dim3 g2(C / 128, (2 * pivot) / 128);
        k2_gemm_jac<<<g2, blk, 0, stream>>>(xJx + (size_t)pivot * C, W, out,
                                            out + (size_t)pivot * C, C);
    }
}

// Round 7
// 483.922 us; speedup vs baseline: 1.4840x; 1.0404x over previous
//
#include <hip/hip_runtime.h>
#include <hip/hip_bf16.h>
#include <cstdint>

typedef __attribute__((ext_vector_type(8))) short short8;
typedef __attribute__((ext_vector_type(4))) float floatx4;

__device__ __forceinline__ float tanh_fast(float x) {
    float e = __expf(2.0f * x);                            // v_exp_f32 path
    return 1.0f - 2.0f * __builtin_amdgcn_rcpf(e + 1.0f);  // saturates to +-1
}

__device__ __forceinline__ unsigned int bf16_bits(float f) {
    __hip_bfloat16 h = __float2bfloat16(f);   // RNE
    return (unsigned int)*reinterpret_cast<unsigned short*>(&h);
}
__device__ __forceinline__ unsigned int pack2(float lo, float hi) {
    return bf16_bits(lo) | (bf16_bits(hi) << 16);
}

// async global->LDS, 16 B per lane. LDS dest is wave-uniform base + lane*16.
__device__ __forceinline__ void async16(const void* g, void* l) {
    __builtin_amdgcn_global_load_lds(
        (const __attribute__((address_space(1))) unsigned int*)g,
        (__attribute__((address_space(3))) unsigned int*)l, 16, 0, 0);
}

// XCD-aware bijective block swizzle, generic grid (nwg % 8 == 0).
// VALIDATED R3/R5: A-panel col-blocks co-resident on one XCD L2
// (k2 FETCH 565->165->98 MB).
__device__ __forceinline__ void swizzle_tile_bm(int& row0, int& col0, int bm) {
    const int gx   = gridDim.x;
    const int nwg  = gx * gridDim.y;
    const int flat = blockIdx.y * gx + blockIdx.x;
    const int swz  = (flat & 7) * (nwg >> 3) + (flat >> 3);
    col0 = (swz % gx) * bm;
    row0 = (swz / gx) * bm;
}

// ===========================================================================
// FAST PATH (needs 98 MB workspace): bf16 pre-pass + 256^2 phase-split GEMMs
// ===========================================================================

// ---------------------------------------------------------------------------
// cvt_prep: X(f32)->Xb(bf16); G(f32, interleaved)->Mb(bf16, de-interleaved
// M[2p+kk][j] = G[p][2j+kk]); W(f32)->Wb(bf16). 16 f32/thread.
// ---------------------------------------------------------------------------
__global__ __launch_bounds__(256) void cvt_prep(
    const float* __restrict__ X, const float* __restrict__ G,
    const float* __restrict__ W,
    short* __restrict__ Xb, short* __restrict__ Mb, short* __restrict__ Wb,
    int nbX, int nbG)
{
    const int tid = threadIdx.x;
    const int b   = blockIdx.x;
    if (b < nbX) {                       // ---- X straight convert
        const size_t e = ((size_t)b * 256 + tid) * 16;
        const float4 f0 = *(const float4*)(X + e);
        const float4 f1 = *(const float4*)(X + e + 4);
        const float4 f2 = *(const float4*)(X + e + 8);
        const float4 f3 = *(const float4*)(X + e + 12);
        uint4 o0, o1;
        o0.x = pack2(f0.x, f0.y); o0.y = pack2(f0.z, f0.w);
        o0.z = pack2(f1.x, f1.y); o0.w = pack2(f1.z, f1.w);
        o1.x = pack2(f2.x, f2.y); o1.y = pack2(f2.z, f2.w);
        o1.z = pack2(f3.x, f3.y); o1.w = pack2(f3.z, f3.w);
        *(uint4*)(Xb + e)     = o0;
        *(uint4*)(Xb + e + 8) = o1;
    } else if (b < nbX + nbG) {          // ---- G de-interleave
        const size_t s = (size_t)(b - nbX) * 256 + tid;  // 16-float segment
        const size_t p = s >> 7;                         // G row (pair-row)
        const int    c = (int)(s & 127);                 // segment in row
        const float* src = G + p * 2048 + (size_t)c * 16;
        const float4 f0 = *(const float4*)(src);         // [j0k0 j0k1 j1k0 j1k1]
        const float4 f1 = *(const float4*)(src + 4);
        const float4 f2 = *(const float4*)(src + 8);
        const float4 f3 = *(const float4*)(src + 12);
        uint4 E, O;
        E.x = pack2(f0.x, f0.z); E.y = pack2(f1.x, f1.z);
        E.z = pack2(f2.x, f2.z); E.w = pack2(f3.x, f3.z);
        O.x = pack2(f0.y, f0.w); O.y = pack2(f1.y, f1.w);
        O.z = pack2(f2.y, f2.w); O.w = pack2(f3.y, f3.w);
        *(uint4*)(Mb + (2 * p)     * 1024 + (size_t)c * 8) = E;   // kk=0
        *(uint4*)(Mb + (2 * p + 1) * 1024 + (size_t)c * 8) = O;   // kk=1
    } else {                             // ---- W straight convert
        const size_t e = ((size_t)(b - nbX - nbG) * 256 + tid) * 16;
        const float4 f0 = *(const float4*)(W + e);
        const float4 f1 = *(const float4*)(W + e + 4);
        const float4 f2 = *(const float4*)(W + e + 8);
        const float4 f3 = *(const float4*)(W + e + 12);
        uint4 o0, o1;
        o0.x = pack2(f0.x, f0.y); o0.y = pack2(f0.z, f0.w);
        o0.z = pack2(f1.x, f1.y); o0.w = pack2(f1.z, f1.w);
        o1.x = pack2(f2.x, f2.y); o1.y = pack2(f2.z, f2.w);
        o1.z = pack2(f3.x, f3.y); o1.w = pack2(f3.z, f3.w);
        *(uint4*)(Wb + e)     = o0;
        *(uint4*)(Wb + e + 8) = o1;
    }
}

// ---------------------------------------------------------------------------
// 256^2 GEMM core: BM=BN=256, BK=64, 8 waves (2M x 4N), 512 threads.
// LDS: double-buffered A[2][256][64] + B[2][256][64] bf16 = 128 KiB.
// Per K-tile: stage next tile FIRST (8 async16/thread), hoist 8 B-frag
// ds_reads, 4 phases of {4 A-reads -> setprio(1) -> 16 MFMA -> setprio(0)},
// then ONE vmcnt(0) (drains loads issued ~full-tile earlier => effectively
// counted) + ONE raw s_barrier per K-tile.
//
// Race-freedom: slot (t+1)&1 staged in iter t was last READ in iter t-1,
// fenced by iter t-1's end barrier; reads of slot t&1 are fenced by iter
// t-1's vmcnt(0)+barrier; ds_read->MFMA waits are compiler-managed.
//
// T2 swizzle (VALIDATED R5: conflicts 25.2M -> 0): LDS dest linear; global
// source pre-permuted so slot s of row r holds chunk s^(r&7); reads XOR
// the slot with (row&7) = (l15&7).
// ---------------------------------------------------------------------------
#define STAGE256(dst_d, kt)                                                    \
    {                                                                          \
        const int koff = (kt) * 64;                                            \
        _Pragma("unroll")                                                      \
        for (int i = 0; i < 4; ++i) {                                          \
            async16(Ag + (size_t)(i * 64) * K + koff,                          \
                    As + (dst_d) * 16384 + (i * 64 + wave * 8) * 64);          \
            async16(Bg + (size_t)(i * 64) * K + koff,                          \
                    Bs + (dst_d) * 16384 + (i * 64 + wave * 8) * 64);          \
        }                                                                      \
    }

#define GEMM256_MAIN()                                                         \
    {                                                                          \
        const int NT = K >> 6;                                                 \
        STAGE256(0, 0)                                                         \
        asm volatile("s_waitcnt vmcnt(0)" ::: "memory");                       \
        __builtin_amdgcn_s_barrier();                                          \
        for (int t = 0; t < NT; ++t) {                                         \
            const int d = t & 1;                                               \
            if (t + 1 < NT) STAGE256(d ^ 1, t + 1)                             \
            const short* Ad = As + d * 16384;                                  \
            const short* Bd = Bs + d * 16384;                                  \
            short8 bfr[4][2];                                                  \
            _Pragma("unroll")                                                  \
            for (int n = 0; n < 4; ++n)                                        \
                _Pragma("unroll")                                              \
                for (int ki = 0; ki < 2; ++ki)                                 \
                    bfr[n][ki] = *(const short8*)&Bd[b_base + n * 1024 +       \
                                     (((ki * 4 + quad) ^ rxor) * 8)];          \
            _Pragma("unroll")                                                  \
            for (int p = 0; p < 4; ++p) {                                      \
                short8 afr[2][2];                                              \
                _Pragma("unroll")                                              \
                for (int a2 = 0; a2 < 2; ++a2)                                 \
                    _Pragma("unroll")                                          \
                    for (int ki = 0; ki < 2; ++ki)                             \
                        afr[a2][ki] = *(const short8*)&Ad[a_base +             \
                            (p * 2 + a2) * 1024 +                              \
                            (((ki * 4 + quad) ^ rxor) * 8)];                   \
                __builtin_amdgcn_s_setprio(1);                                 \
                _Pragma("unroll")                                              \
                for (int a2 = 0; a2 < 2; ++a2)                                 \
                    _Pragma("unroll")                                          \
                    for (int n = 0; n < 4; ++n)                                \
                        _Pragma("unroll")                                      \
                        for (int ki = 0; ki < 2; ++ki)                         \
                            acc[p * 2 + a2][n] =                               \
                                __builtin_amdgcn_mfma_f32_16x16x32_bf16(       \
                                    afr[a2][ki], bfr[n][ki],                   \
                                    acc[p * 2 + a2][n], 0, 0, 0);              \
                __builtin_amdgcn_s_setprio(0);                                 \
            }                                                                  \
            asm volatile("s_waitcnt vmcnt(0)" ::: "memory");                   \
            __builtin_amdgcn_s_barrier();                                      \
        }                                                                      \
    }

// K1c: out[0:pivot] = tanh(Xb @ Wb^T + b)
__global__ __launch_bounds__(512, 1) void k1c_gemm_tanh(
    const short* __restrict__ A,      // Xb  (pivot x 1024 bf16)
    const short* __restrict__ B,      // Wb  (1024 x 1024 bf16)
    const float* __restrict__ Bv,
    float* __restrict__ out, int K)
{
    __shared__ __align__(16) short As[2 * 256 * 64];
    __shared__ __align__(16) short Bs[2 * 256 * 64];

    const int tid  = threadIdx.x;
    const int lane = tid & 63;
    const int wave = tid >> 6;
    const int wr = wave >> 2, wc = wave & 3;   // 2M x 4N waves

    int row0, col0;
    swizzle_tile_bm(row0, col0, 256);

    const int l15  = lane & 15;
    const int quad = lane >> 4;
    const int rxor = l15 & 7;
    const int a_base = (wr * 128 + l15) * 64;
    const int b_base = (wc * 64  + l15) * 64;

    const int lrow = lane >> 3;
    const int lcol = lane & 7;
    const int cswz = lcol ^ lrow;              // T2 pre-swizzled global chunk
    const short* Ag = A + (size_t)(row0 + wave * 8 + lrow) * K + cswz * 8;
    const short* Bg = B + (size_t)(col0 + wave * 8 + lrow) * K + cswz * 8;

    floatx4 acc[8][4];
#pragma unroll
    for (int a = 0; a < 8; ++a)
#pragma unroll
        for (int n = 0; n < 4; ++n) acc[a][n] = (floatx4){0.f, 0.f, 0.f, 0.f};

    GEMM256_MAIN()

    float bv[4];
#pragma unroll
    for (int n = 0; n < 4; ++n)
        bv[n] = Bv[col0 + wc * 64 + n * 16 + l15];

#pragma unroll
    for (int a = 0; a < 8; ++a) {
        const int rbase = row0 + wr * 128 + a * 16 + quad * 4;
#pragma unroll
        for (int n = 0; n < 4; ++n) {
            const int c = col0 + wc * 64 + n * 16 + l15;
#pragma unroll
            for (int r = 0; r < 4; ++r)
                out[(size_t)(rbase + r) * 1024 + c] = tanh_fast(acc[a][n][r] + bv[n]);
        }
    }
}

// K2c: C2 = Mb @ Wb^T; out2[2p+(i>=512)][(2i+kk)%1024] = (1-h^2)*C2[2p+kk][i]
__global__ __launch_bounds__(512, 1) void k2c_gemm_jac(
    const short* __restrict__ A,      // Mb  (2*pivot x 1024 bf16, de-interleaved)
    const short* __restrict__ B,      // Wb
    const float* __restrict__ Hout,   // hAx rows [0, pivot)
    float* __restrict__ out2, int K)
{
    __shared__ __align__(16) short As[2 * 256 * 64];
    __shared__ __align__(16) short Bs[2 * 256 * 64];

    const int tid  = threadIdx.x;
    const int lane = tid & 63;
    const int wave = tid >> 6;
    const int wr = wave >> 2, wc = wave & 3;

    int r0, col0;
    swizzle_tile_bm(r0, col0, 256);

    const int l15  = lane & 15;
    const int quad = lane >> 4;
    const int rxor = l15 & 7;
    const int a_base = (wr * 128 + l15) * 64;
    const int b_base = (wc * 64  + l15) * 64;

    const int lrow = lane >> 3;
    const int lcol = lane & 7;
    const int cswz = lcol ^ lrow;
    const short* Ag = A + (size_t)(r0 + wave * 8 + lrow) * K + cswz * 8;
    const short* Bg = B + (size_t)(col0 + wave * 8 + lrow) * K + cswz * 8;

    floatx4 acc[8][4];
#pragma unroll
    for (int a = 0; a < 8; ++a)
#pragma unroll
        for (int n = 0; n < 4; ++n) acc[a][n] = (floatx4){0.f, 0.f, 0.f, 0.f};

    GEMM256_MAIN()

    // epilogue: acc regs (0,1)/(2,3) are M-rows (2p, 2p+1) -> one float2 store
#pragma unroll
    for (int a = 0; a < 8; ++a) {
        const int rb = r0 + wr * 128 + a * 16 + quad * 4;  // even
#pragma unroll
        for (int n = 0; n < 4; ++n) {
            const int i = col0 + wc * 64 + n * 16 + l15;
            const int shift = (i >= 512) ? 1 : 0;
            const int ccol = 2 * i - shift * 1024;
#pragma unroll
            for (int pr = 0; pr < 2; ++pr) {
                const int re = rb + pr * 2;                // even row = 2p
                const int p  = re >> 1;
                const float h  = Hout[(size_t)p * 1024 + i];
                const float hp = 1.0f - h * h;
                float2 st;
                st.x = hp * acc[a][n][pr * 2];             // kk=0 -> col 2i
                st.y = hp * acc[a][n][pr * 2 + 1];         // kk=1 -> col 2i+1
                *(float2*)&out2[(size_t)(re + shift) * 1024 + ccol] = st;
            }
        }
    }
}

// ===========================================================================
// FALLBACK PATH (R3 kernels, harness-verified): f32 reg-staged, LDS pad 72
// ===========================================================================
#define LDS_STRIDE 72

__device__ __forceinline__ void swizzle_tile(int& row0, int& col0) {
    const int nwg  = gridDim.x * gridDim.y;
    const int flat = blockIdx.y * gridDim.x + blockIdx.x;
    const int swz  = (flat & 7) * (nwg >> 3) + (flat >> 3);
    col0 = (swz & 7) * 128;
    row0 = (swz >> 3) * 128;
}

__global__ __launch_bounds__(256) void k1_gemm_tanh(
    const float* __restrict__ X, const float* __restrict__ W,
    const float* __restrict__ Bv, float* __restrict__ out, int K)
{
    __shared__ __align__(16) short As[128 * LDS_STRIDE];
    __shared__ __align__(16) short Bs[128 * LDS_STRIDE];
    const int tid  = threadIdx.x;
    const int lane = tid & 63;
    const int wave = tid >> 6;
    const int wm = wave & 1, wn = wave >> 1;
    int row0, col0;
    swizzle_tile(row0, col0);
    const int l15  = lane & 15;
    const int quad = lane >> 4;
    const int a_base = (wm * 64 + l15) * LDS_STRIDE;
    const int b_base = (wn * 64 + l15) * LDS_STRIDE;

    floatx4 acc[4][4];
#pragma unroll
    for (int a = 0; a < 4; ++a)
#pragma unroll
        for (int b = 0; b < 4; ++b) acc[a][b] = (floatx4){0.f, 0.f, 0.f, 0.f};

    for (int k0 = 0; k0 < K; k0 += 64) {
        __syncthreads();
#pragma unroll
        for (int i = 0; i < 8; ++i) {
            const int g = i * 256 + tid;
            const int r = g >> 4, c = g & 15;
            const float4 va = *(const float4*)(X + (size_t)(row0 + r) * K + k0 + c * 4);
            const float4 vb = *(const float4*)(W + (size_t)(col0 + r) * K + k0 + c * 4);
            uint2 ea, eb;
            ea.x = pack2(va.x, va.y); ea.y = pack2(va.z, va.w);
            eb.x = pack2(vb.x, vb.y); eb.y = pack2(vb.z, vb.w);
            *(uint2*)&As[r * LDS_STRIDE + c * 4] = ea;
            *(uint2*)&Bs[r * LDS_STRIDE + c * 4] = eb;
        }
        __syncthreads();
#pragma unroll
        for (int ki = 0; ki < 2; ++ki) {
            const int kx = ki * 32 + quad * 8;
            short8 af[4], bf[4];
#pragma unroll
            for (int s = 0; s < 4; ++s)
                af[s] = *(const short8*)&As[a_base + s * 16 * LDS_STRIDE + kx];
#pragma unroll
            for (int s = 0; s < 4; ++s)
                bf[s] = *(const short8*)&Bs[b_base + s * 16 * LDS_STRIDE + kx];
#pragma unroll
            for (int a = 0; a < 4; ++a)
#pragma unroll
                for (int b = 0; b < 4; ++b)
                    acc[a][b] = __builtin_amdgcn_mfma_f32_16x16x32_bf16(
                        af[a], bf[b], acc[a][b], 0, 0, 0);
        }
    }

    float bv[4];
#pragma unroll
    for (int b = 0; b < 4; ++b)
        bv[b] = Bv[col0 + wn * 64 + b * 16 + l15];
#pragma unroll
    for (int a = 0; a < 4; ++a) {
        const int rbase = row0 + wm * 64 + a * 16 + quad * 4;
#pragma unroll
        for (int b = 0; b < 4; ++b) {
            const int n = col0 + wn * 64 + b * 16 + l15;
#pragma unroll
            for (int r = 0; r < 4; ++r)
                out[(size_t)(rbase + r) * 1024 + n] = tanh_fast(acc[a][b][r] + bv[b]);
        }
    }
}

__global__ __launch_bounds__(256) void k2_gemm_jac(
    const float* __restrict__ G, const float* __restrict__ W,
    const float* __restrict__ Hout, float* __restrict__ out2, int K)
{
    __shared__ __align__(16) short As[128 * LDS_STRIDE];
    __shared__ __align__(16) short Bs[128 * LDS_STRIDE];
    const int tid  = threadIdx.x;
    const int lane = tid & 63;
    const int wave = tid >> 6;
    const int wm = wave & 1, wn = wave >> 1;
    int r0, col0;
    swizzle_tile(r0, col0);
    const int p0 = r0 >> 1;
    const int l15  = lane & 15;
    const int quad = lane >> 4;
    const int a_base = (wm * 64 + l15) * LDS_STRIDE;
    const int b_base = (wn * 64 + l15) * LDS_STRIDE;

    floatx4 acc[4][4];
#pragma unroll
    for (int a = 0; a < 4; ++a)
#pragma unroll
        for (int b = 0; b < 4; ++b) acc[a][b] = (floatx4){0.f, 0.f, 0.f, 0.f};

    for (int k0 = 0; k0 < K; k0 += 64) {
        __syncthreads();
#pragma unroll
        for (int i = 0; i < 8; ++i) {
            const int g = i * 256 + tid;
            const int r = g >> 4, c = g & 15;
            const float4 vb = *(const float4*)(W + (size_t)(col0 + r) * K + k0 + c * 4);
            uint2 eb;
            eb.x = pack2(vb.x, vb.y); eb.y = pack2(vb.z, vb.w);
            *(uint2*)&Bs[r * LDS_STRIDE + c * 4] = eb;
        }
#pragma unroll
        for (int i = 0; i < 4; ++i) {
            const int g = i * 256 + tid;
            const int q = g >> 4, d = g & 15;
            const float* src = G + (size_t)(p0 + q) * 2048 + 2 * k0 + d * 8;
            const float4 u0 = *(const float4*)src;
            const float4 u1 = *(const float4*)(src + 4);
            uint2 E, O;
            E.x = pack2(u0.x, u0.z); E.y = pack2(u1.x, u1.z);
            O.x = pack2(u0.y, u0.w); O.y = pack2(u1.y, u1.w);
            *(uint2*)&As[(2 * q)     * LDS_STRIDE + d * 4] = E;
            *(uint2*)&As[(2 * q + 1) * LDS_STRIDE + d * 4] = O;
        }
        __syncthreads();
#pragma unroll
        for (int ki = 0; ki < 2; ++ki) {
            const int kx = ki * 32 + quad * 8;
            short8 af[4], bf[4];
#pragma unroll
            for (int s = 0; s < 4; ++s)
                af[s] = *(const short8*)&As[a_base + s * 16 * LDS_STRIDE + kx];
#pragma unroll
            for (int s = 0; s < 4; ++s)
                bf[s] = *(const short8*)&Bs[b_base + s * 16 * LDS_STRIDE + kx];
#pragma unroll
            for (int a = 0; a < 4; ++a)
#pragma unroll
                for (int b = 0; b < 4; ++b)
                    acc[a][b] = __builtin_amdgcn_mfma_f32_16x16x32_bf16(
                        af[a], bf[b], acc[a][b], 0, 0, 0);
        }
    }

#pragma unroll
    for (int a = 0; a < 4; ++a) {
        const int rb = r0 + wm * 64 + a * 16 + quad * 4;
#pragma unroll
        for (int b = 0; b < 4; ++b) {
            const int i = col0 + wn * 64 + b * 16 + l15;
            const int shift = (i >= 512) ? 1 : 0;
            const int ccol = 2 * i - shift * 1024;
#pragma unroll
            for (int pr = 0; pr < 2; ++pr) {
                const int re = rb + pr * 2;
                const int p  = re >> 1;
                const float h  = Hout[(size_t)p * 1024 + i];
                const float hp = 1.0f - h * h;
                float2 st;
                st.x = hp * acc[a][b][pr * 2];
                st.y = hp * acc[a][b][pr * 2 + 1];
                *(float2*)&out2[(size_t)(re + shift) * 1024 + ccol] = st;
            }
        }
    }
}

extern "C" void kernel_launch(void* const* d_in, const int* in_sizes, int n_in,
                              void* d_out, int out_size, void* d_ws, size_t ws_size,
                              hipStream_t stream) {
    const float* xJx = (const float*)d_in[0];
    const float* W   = (const float*)d_in[1];
    const float* bv  = (const float*)d_in[2];
    float* out = (float*)d_out;

    const int C     = 1024;
    const int rows3 = in_sizes[0] / C;   // 3*pivot
    const int pivot = rows3 / 3;         // 16384

    const size_t szXb = (size_t)pivot * C * 2;          // 32 MB
    const size_t szMb = (size_t)2 * pivot * C * 2;      // 64 MB
    const size_t szWb = (size_t)C * C * 2;              //  2 MB

    if (ws_size >= szXb + szMb + szWb) {
        short* Xb = (short*)d_ws;
        short* Mb = (short*)((char*)d_ws + szXb);
        short* Wb = (short*)((char*)d_ws + szXb + szMb);

        const int nbX = (pivot * C) / 4096;             // 4096
        const int nbG = (pivot * 2 * C) / 4096;         // 8192
        const int nbW = (C * C) / 4096;                 //  256
        cvt_prep<<<dim3(nbX + nbG + nbW), dim3(256), 0, stream>>>(
            xJx, xJx + (size_t)pivot * C, W, Xb, Mb, Wb, nbX, nbG);

        dim3 g1(C / 256, pivot / 256);                  // 4 x 64 = 256 blocks
        k1c_gemm_tanh<<<g1, dim3(512), 0, stream>>>(Xb, Wb, bv, out, C);

        dim3 g2(C / 256, (2 * pivot) / 256);            // 4 x 128 = 512 blocks
        k2c_gemm_jac<<<g2, dim3(512), 0, stream>>>(Mb, Wb, out,
                                                   out + (size_t)pivot * C, C);
    } else {
        dim3 g1(C / 128, pivot / 128);
        k1_gemm_tanh<<<g1, dim3(256), 0, stream>>>(xJx, W, bv, out, C);
        dim3 g2(C / 128, (2 * pivot) / 128);
        k2_gemm_jac<<<g2, dim3(256), 0, stream>>>(xJx + (size_t)pivot * C, W, out,
                                                  out + (size_t)pivot * C, C);
    }
}

// Round 10
// 476.495 us; speedup vs baseline: 1.5072x; 1.0156x over previous
//
#include <hip/hip_runtime.h>
#include <hip/hip_bf16.h>
#include <cstdint>

typedef __attribute__((ext_vector_type(8))) short short8;
typedef __attribute__((ext_vector_type(4))) float floatx4;

__device__ __forceinline__ float tanh_fast(float x) {
    float e = __expf(2.0f * x);                            // v_exp_f32 path
    return 1.0f - 2.0f * __builtin_amdgcn_rcpf(e + 1.0f);  // saturates to +-1
}

__device__ __forceinline__ unsigned int bf16_bits(float f) {
    __hip_bfloat16 h = __float2bfloat16(f);   // RNE
    return (unsigned int)*reinterpret_cast<unsigned short*>(&h);
}
__device__ __forceinline__ unsigned int pack2(float lo, float hi) {
    return bf16_bits(lo) | (bf16_bits(hi) << 16);
}

// async global->LDS, 16 B per lane. LDS dest is wave-uniform base + lane*16.
__device__ __forceinline__ void async16(const void* g, void* l) {
    __builtin_amdgcn_global_load_lds(
        (const __attribute__((address_space(1))) unsigned int*)g,
        (__attribute__((address_space(3))) unsigned int*)l, 16, 0, 0);
}

// XCD-aware bijective block swizzle, generic grid (nwg % 8 == 0).
// VALIDATED R3/R5: A-panel col-blocks co-resident on one XCD L2
// (k2 FETCH 565->165->98 MB).
__device__ __forceinline__ void swizzle_tile_bm(int& row0, int& col0, int bm) {
    const int gx   = gridDim.x;
    const int nwg  = gx * gridDim.y;
    const int flat = blockIdx.y * gx + blockIdx.x;
    const int swz  = (flat & 7) * (nwg >> 3) + (flat >> 3);
    col0 = (swz % gx) * bm;
    row0 = (swz / gx) * bm;
}

// ===========================================================================
// FAST PATH (needs 98 MB workspace): bf16 pre-pass + 256^2 8-phase GEMMs
// ===========================================================================

// ---------------------------------------------------------------------------
// cvt_prep: X(f32)->Xb(bf16); G(f32, interleaved)->Mb(bf16, de-interleaved
// M[2p+kk][j] = G[p][2j+kk]); W(f32)->Wb(bf16). 16 f32/thread.
// ---------------------------------------------------------------------------
__global__ __launch_bounds__(256) void cvt_prep(
    const float* __restrict__ X, const float* __restrict__ G,
    const float* __restrict__ W,
    short* __restrict__ Xb, short* __restrict__ Mb, short* __restrict__ Wb,
    int nbX, int nbG)
{
    const int tid = threadIdx.x;
    const int b   = blockIdx.x;
    if (b < nbX) {                       // ---- X straight convert
        const size_t e = ((size_t)b * 256 + tid) * 16;
        const float4 f0 = *(const float4*)(X + e);
        const float4 f1 = *(const float4*)(X + e + 4);
        const float4 f2 = *(const float4*)(X + e + 8);
        const float4 f3 = *(const float4*)(X + e + 12);
        uint4 o0, o1;
        o0.x = pack2(f0.x, f0.y); o0.y = pack2(f0.z, f0.w);
        o0.z = pack2(f1.x, f1.y); o0.w = pack2(f1.z, f1.w);
        o1.x = pack2(f2.x, f2.y); o1.y = pack2(f2.z, f2.w);
        o1.z = pack2(f3.x, f3.y); o1.w = pack2(f3.z, f3.w);
        *(uint4*)(Xb + e)     = o0;
        *(uint4*)(Xb + e + 8) = o1;
    } else if (b < nbX + nbG) {          // ---- G de-interleave
        const size_t s = (size_t)(b - nbX) * 256 + tid;  // 16-float segment
        const size_t p = s >> 7;                         // G row (pair-row)
        const int    c = (int)(s & 127);                 // segment in row
        const float* src = G + p * 2048 + (size_t)c * 16;
        const float4 f0 = *(const float4*)(src);         // [j0k0 j0k1 j1k0 j1k1]
        const float4 f1 = *(const float4*)(src + 4);
        const float4 f2 = *(const float4*)(src + 8);
        const float4 f3 = *(const float4*)(src + 12);
        uint4 E, O;
        E.x = pack2(f0.x, f0.z); E.y = pack2(f1.x, f1.z);
        E.z = pack2(f2.x, f2.z); E.w = pack2(f3.x, f3.z);
        O.x = pack2(f0.y, f0.w); O.y = pack2(f1.y, f1.w);
        O.z = pack2(f2.y, f2.w); O.w = pack2(f3.y, f3.w);
        *(uint4*)(Mb + (2 * p)     * 1024 + (size_t)c * 8) = E;   // kk=0
        *(uint4*)(Mb + (2 * p + 1) * 1024 + (size_t)c * 8) = O;   // kk=1
    } else {                             // ---- W straight convert
        const size_t e = ((size_t)(b - nbX - nbG) * 256 + tid) * 16;
        const float4 f0 = *(const float4*)(W + e);
        const float4 f1 = *(const float4*)(W + e + 4);
        const float4 f2 = *(const float4*)(W + e + 8);
        const float4 f3 = *(const float4*)(W + e + 12);
        uint4 o0, o1;
        o0.x = pack2(f0.x, f0.y); o0.y = pack2(f0.z, f0.w);
        o0.z = pack2(f1.x, f1.y); o0.w = pack2(f1.z, f1.w);
        o1.x = pack2(f2.x, f2.y); o1.y = pack2(f2.z, f2.w);
        o1.z = pack2(f3.x, f3.y); o1.w = pack2(f3.z, f3.w);
        *(uint4*)(Wb + e)     = o0;
        *(uint4*)(Wb + e + 8) = o1;
    }
}

// ---------------------------------------------------------------------------
// 256^2 8-PHASE GEMM core: BM=BN=256, BK=64, 8 waves (2M x 4N), 512 threads.
// LDS: double-buffered A[2][256][64] + B[2][256][64] bf16 = 128 KiB.
//
// Per K-tile, 4 phases (16 MFMA/wave each = one 32-row A-quadrant x 64 cols):
//   { ds_read frags (12 at p0 incl. B-frags, else 4); stage A-half at p0 /
//     B-half at p1 -> s_barrier -> setprio(1) -> 16 MFMA -> setprio(0)
//     -> s_barrier }
// (compiler inserts exact counted lgkmcnt before each MFMA; no inline-asm
// lgkm hints needed -- rule #18 risk removed)
// End of tile: ONE vmcnt(0) (loads were issued >=2 phases ~1200+ cyc earlier
// -> effectively counted) + tile-boundary s_barrier.  [T3/T4 discipline,
// m196/m218/m248: the per-phase interleave is the lever, +29% at K=1024]
//
// Race-freedom: uniform control flow (all barriers under uniform trip-count
// loops); buf d^1 staged in iter t was last read before iter t-1's tile-end
// barrier (each phase's ds_reads drain before its MFMAs); reads of buf d
// fenced by iter t-1's vmcnt(0)+barrier.
//
// T2 swizzle (VALIDATED R5: conflicts 25.2M -> 0): LDS dest linear; global
// source pre-permuted so slot s of row r holds chunk s^(r&7); reads XOR
// the slot with (row&7) = (l15&7).
// ---------------------------------------------------------------------------
#define STAGE_A256(dst_d, kt)                                                  \
    {                                                                          \
        _Pragma("unroll")                                                      \
        for (int i = 0; i < 4; ++i)                                            \
            async16(Ag + (size_t)(i * 64) * K + (kt) * 64,                     \
                    As + (dst_d) * 16384 + (i * 64 + wave * 8) * 64);          \
    }
#define STAGE_B256(dst_d, kt)                                                  \
    {                                                                          \
        _Pragma("unroll")                                                      \
        for (int i = 0; i < 4; ++i)                                            \
            async16(Bg + (size_t)(i * 64) * K + (kt) * 64,                     \
                    Bs + (dst_d) * 16384 + (i * 64 + wave * 8) * 64);          \
    }

#define GEMM256_8PH()                                                          \
    {                                                                          \
        const int NT = K >> 6;                                                 \
        STAGE_A256(0, 0) STAGE_B256(0, 0)                                      \
        asm volatile("s_waitcnt vmcnt(0)" ::: "memory");                       \
        __builtin_amdgcn_s_barrier();                                          \
        for (int t = 0; t < NT; ++t) {                                         \
            const int d = t & 1;                                               \
            const short* Ad = As + d * 16384;                                  \
            const short* Bd = Bs + d * 16384;                                  \
            short8 bfr[4][2];                                                  \
            _Pragma("unroll")                                                  \
            for (int p = 0; p < 4; ++p) {                                      \
                if (p == 0) {                                                  \
                    _Pragma("unroll")                                          \
                    for (int n = 0; n < 4; ++n)                                \
                        _Pragma("unroll")                                      \
                        for (int ki = 0; ki < 2; ++ki)                         \
                            bfr[n][ki] = *(const short8*)&Bd[b_base +          \
                                n * 1024 + (((ki * 4 + quad) ^ rxor) * 8)];    \
                    if (t + 1 < NT) STAGE_A256(d ^ 1, t + 1)                   \
                } else if (p == 1) {                                           \
                    if (t + 1 < NT) STAGE_B256(d ^ 1, t + 1)                   \
                }                                                              \
                short8 afr[2][2];                                              \
                _Pragma("unroll")                                              \
                for (int a2 = 0; a2 < 2; ++a2)                                 \
                    _Pragma("unroll")                                          \
                    for (int ki = 0; ki < 2; ++ki)                             \
                        afr[a2][ki] = *(const short8*)&Ad[a_base +             \
                            (p * 2 + a2) * 1024 +                              \
                            (((ki * 4 + quad) ^ rxor) * 8)];                   \
                __builtin_amdgcn_s_barrier();                                  \
                __builtin_amdgcn_s_setprio(1);                                 \
                _Pragma("unroll")                                              \
                for (int a2 = 0; a2 < 2; ++a2)                                 \
                    _Pragma("unroll")                                          \
                    for (int n = 0; n < 4; ++n)                                \
                        _Pragma("unroll")                                      \
                        for (int ki = 0; ki < 2; ++ki)                         \
                            acc[p * 2 + a2][n] =                               \
                                __builtin_amdgcn_mfma_f32_16x16x32_bf16(       \
                                    afr[a2][ki], bfr[n][ki],                   \
                                    acc[p * 2 + a2][n], 0, 0, 0);              \
                __builtin_amdgcn_s_setprio(0);                                 \
                if (p < 3) __builtin_amdgcn_s_barrier();                       \
            }                                                                  \
            asm volatile("s_waitcnt vmcnt(0)" ::: "memory");                   \
            __builtin_amdgcn_s_barrier();                                      \
        }                                                                      \
    }

// K1c: out[0:pivot] = tanh(Xb @ Wb^T + b)
__global__ __launch_bounds__(512, 1) void k1c_gemm_tanh(
    const short* __restrict__ A,      // Xb  (pivot x 1024 bf16)
    const short* __restrict__ B,      // Wb  (1024 x 1024 bf16)
    const float* __restrict__ Bv,
    float* __restrict__ out, int K)
{
    __shared__ __align__(16) short As[2 * 256 * 64];
    __shared__ __align__(16) short Bs[2 * 256 * 64];

    const int tid  = threadIdx.x;
    const int lane = tid & 63;
    const int wave = tid >> 6;
    const int wr = wave >> 2, wc = wave & 3;   // 2M x 4N waves

    int row0, col0;
    swizzle_tile_bm(row0, col0, 256);

    const int l15  = lane & 15;
    const int quad = lane >> 4;
    const int rxor = l15 & 7;
    const int a_base = (wr * 128 + l15) * 64;
    const int b_base = (wc * 64  + l15) * 64;

    const int lrow = lane >> 3;
    const int lcol = lane & 7;
    const int cswz = lcol ^ lrow;              // T2 pre-swizzled global chunk
    const short* Ag = A + (size_t)(row0 + wave * 8 + lrow) * K + cswz * 8;
    const short* Bg = B + (size_t)(col0 + wave * 8 + lrow) * K + cswz * 8;

    floatx4 acc[8][4];
#pragma unroll
    for (int a = 0; a < 8; ++a)
#pragma unroll
        for (int n = 0; n < 4; ++n) acc[a][n] = (floatx4){0.f, 0.f, 0.f, 0.f};

    GEMM256_8PH()

    float bv[4];
#pragma unroll
    for (int n = 0; n < 4; ++n)
        bv[n] = Bv[col0 + wc * 64 + n * 16 + l15];

#pragma unroll
    for (int a = 0; a < 8; ++a) {
        const int rbase = row0 + wr * 128 + a * 16 + quad * 4;
#pragma unroll
        for (int n = 0; n < 4; ++n) {
            const int c = col0 + wc * 64 + n * 16 + l15;
#pragma unroll
            for (int r = 0; r < 4; ++r)
                out[(size_t)(rbase + r) * 1024 + c] = tanh_fast(acc[a][n][r] + bv[n]);
        }
    }
}

// K2c: C2 = Mb @ Wb^T; out2[2p+(i>=512)][(2i+kk)%1024] = (1-h^2)*C2[2p+kk][i]
__global__ __launch_bounds__(512, 1) void k2c_gemm_jac(
    const short* __restrict__ A,      // Mb  (2*pivot x 1024 bf16, de-interleaved)
    const short* __restrict__ B,      // Wb
    const float* __restrict__ Hout,   // hAx rows [0, pivot)
    float* __restrict__ out2, int K)
{
    __shared__ __align__(16) short As[2 * 256 * 64];
    __shared__ __align__(16) short Bs[2 * 256 * 64];

    const int tid  = threadIdx.x;
    const int lane = tid & 63;
    const int wave = tid >> 6;
    const int wr = wave >> 2, wc = wave & 3;

    int r0, col0;
    swizzle_tile_bm(r0, col0, 256);

    const int l15  = lane & 15;
    const int quad = lane >> 4;
    const int rxor = l15 & 7;
    const int a_base = (wr * 128 + l15) * 64;
    const int b_base = (wc * 64  + l15) * 64;

    const int lrow = lane >> 3;
    const int lcol = lane & 7;
    const int cswz = lcol ^ lrow;
    const short* Ag = A + (size_t)(r0 + wave * 8 + lrow) * K + cswz * 8;
    const short* Bg = B + (size_t)(col0 + wave * 8 + lrow) * K + cswz * 8;

    floatx4 acc[8][4];
#pragma unroll
    for (int a = 0; a < 8; ++a)
#pragma unroll
        for (int n = 0; n < 4; ++n) acc[a][n] = (floatx4){0.f, 0.f, 0.f, 0.f};

    GEMM256_8PH()

    // epilogue: acc regs (0,1)/(2,3) are M-rows (2p, 2p+1) -> one float2 store
#pragma unroll
    for (int a = 0; a < 8; ++a) {
        const int rb = r0 + wr * 128 + a * 16 + quad * 4;  // even
#pragma unroll
        for (int n = 0; n < 4; ++n) {
            const int i = col0 + wc * 64 + n * 16 + l15;
            const int shift = (i >= 512) ? 1 : 0;
            const int ccol = 2 * i - shift * 1024;
#pragma unroll
            for (int pr = 0; pr < 2; ++pr) {
                const int re = rb + pr * 2;                // even row = 2p
                const int p  = re >> 1;
                const float h  = Hout[(size_t)p * 1024 + i];
                const float hp = 1.0f - h * h;
                float2 st;
                st.x = hp * acc[a][n][pr * 2];             // kk=0 -> col 2i
                st.y = hp * acc[a][n][pr * 2 + 1];         // kk=1 -> col 2i+1
                *(float2*)&out2[(size_t)(re + shift) * 1024 + ccol] = st;
            }
        }
    }
}

// ===========================================================================
// FALLBACK PATH (R3 kernels, harness-verified): f32 reg-staged, LDS pad 72
// ===========================================================================
#define LDS_STRIDE 72

__device__ __forceinline__ void swizzle_tile(int& row0, int& col0) {
    const int nwg  = gridDim.x * gridDim.y;
    const int flat = blockIdx.y * gridDim.x + blockIdx.x;
    const int swz  = (flat & 7) * (nwg >> 3) + (flat >> 3);
    col0 = (swz & 7) * 128;
    row0 = (swz >> 3) * 128;
}

__global__ __launch_bounds__(256) void k1_gemm_tanh(
    const float* __restrict__ X, const float* __restrict__ W,
    const float* __restrict__ Bv, float* __restrict__ out, int K)
{
    __shared__ __align__(16) short As[128 * LDS_STRIDE];
    __shared__ __align__(16) short Bs[128 * LDS_STRIDE];
    const int tid  = threadIdx.x;
    const int lane = tid & 63;
    const int wave = tid >> 6;
    const int wm = wave & 1, wn = wave >> 1;
    int row0, col0;
    swizzle_tile(row0, col0);
    const int l15  = lane & 15;
    const int quad = lane >> 4;
    const int a_base = (wm * 64 + l15) * LDS_STRIDE;
    const int b_base = (wn * 64 + l15) * LDS_STRIDE;

    floatx4 acc[4][4];
#pragma unroll
    for (int a = 0; a < 4; ++a)
#pragma unroll
        for (int b = 0; b < 4; ++b) acc[a][b] = (floatx4){0.f, 0.f, 0.f, 0.f};

    for (int k0 = 0; k0 < K; k0 += 64) {
        __syncthreads();
#pragma unroll
        for (int i = 0; i < 8; ++i) {
            const int g = i * 256 + tid;
            const int r = g >> 4, c = g & 15;
            const float4 va = *(const float4*)(X + (size_t)(row0 + r) * K + k0 + c * 4);
            const float4 vb = *(const float4*)(W + (size_t)(col0 + r) * K + k0 + c * 4);
            uint2 ea, eb;
            ea.x = pack2(va.x, va.y); ea.y = pack2(va.z, va.w);
            eb.x = pack2(vb.x, vb.y); eb.y = pack2(vb.z, vb.w);
            *(uint2*)&As[r * LDS_STRIDE + c * 4] = ea;
            *(uint2*)&Bs[r * LDS_STRIDE + c * 4] = eb;
        }
        __syncthreads();
#pragma unroll
        for (int ki = 0; ki < 2; ++ki) {
            const int kx = ki * 32 + quad * 8;
            short8 af[4], bf[4];
#pragma unroll
            for (int s = 0; s < 4; ++s)
                af[s] = *(const short8*)&As[a_base + s * 16 * LDS_STRIDE + kx];
#pragma unroll
            for (int s = 0; s < 4; ++s)
                bf[s] = *(const short8*)&Bs[b_base + s * 16 * LDS_STRIDE + kx];
#pragma unroll
            for (int a = 0; a < 4; ++a)
#pragma unroll
                for (int b = 0; b < 4; ++b)
                    acc[a][b] = __builtin_amdgcn_mfma_f32_16x16x32_bf16(
                        af[a], bf[b], acc[a][b], 0, 0, 0);
        }
    }

    float bv[4];
#pragma unroll
    for (int b = 0; b < 4; ++b)
        bv[b] = Bv[col0 + wn * 64 + b * 16 + l15];
#pragma unroll
    for (int a = 0; a < 4; ++a) {
        const int rbase = row0 + wm * 64 + a * 16 + quad * 4;
#pragma unroll
        for (int b = 0; b < 4; ++b) {
            const int n = col0 + wn * 64 + b * 16 + l15;
#pragma unroll
            for (int r = 0; r < 4; ++r)
                out[(size_t)(rbase + r) * 1024 + n] = tanh_fast(acc[a][b][r] + bv[b]);
        }
    }
}

__global__ __launch_bounds__(256) void k2_gemm_jac(
    const float* __restrict__ G, const float* __restrict__ W,
    const float* __restrict__ Hout, float* __restrict__ out2, int K)
{
    __shared__ __align__(16) short As[128 * LDS_STRIDE];
    __shared__ __align__(16) short Bs[128 * LDS_STRIDE];
    const int tid  = threadIdx.x;
    const int lane = tid & 63;
    const int wave = tid >> 6;
    const int wm = wave & 1, wn = wave >> 1;
    int r0, col0;
    swizzle_tile(r0, col0);
    const int p0 = r0 >> 1;
    const int l15  = lane & 15;
    const int quad = lane >> 4;
    const int a_base = (wm * 64 + l15) * LDS_STRIDE;
    const int b_base = (wn * 64 + l15) * LDS_STRIDE;

    floatx4 acc[4][4];
#pragma unroll
    for (int a = 0; a < 4; ++a)
#pragma unroll
        for (int b = 0; b < 4; ++b) acc[a][b] = (floatx4){0.f, 0.f, 0.f, 0.f};

    for (int k0 = 0; k0 < K; k0 += 64) {
        __syncthreads();
#pragma unroll
        for (int i = 0; i < 8; ++i) {
            const int g = i * 256 + tid;
            const int r = g >> 4, c = g & 15;
            const float4 vb = *(const float4*)(W + (size_t)(col0 + r) * K + k0 + c * 4);
            uint2 eb;
            eb.x = pack2(vb.x, vb.y); eb.y = pack2(vb.z, vb.w);
            *(uint2*)&Bs[r * LDS_STRIDE + c * 4] = eb;
        }
#pragma unroll
        for (int i = 0; i < 4; ++i) {
            const int g = i * 256 + tid;
            const int q = g >> 4, d = g & 15;
            const float* src = G + (size_t)(p0 + q) * 2048 + 2 * k0 + d * 8;
            const float4 u0 = *(const float4*)src;
            const float4 u1 = *(const float4*)(src + 4);
            uint2 E, O;
            E.x = pack2(u0.x, u0.z); E.y = pack2(u1.x, u1.z);
            O.x = pack2(u0.y, u0.w); O.y = pack2(u1.y, u1.w);
            *(uint2*)&As[(2 * q)     * LDS_STRIDE + d * 4] = E;
            *(uint2*)&As[(2 * q + 1) * LDS_STRIDE + d * 4] = O;
        }
        __syncthreads();
#pragma unroll
        for (int ki = 0; ki < 2; ++ki) {
            const int kx = ki * 32 + quad * 8;
            short8 af[4], bf[4];
#pragma unroll
            for (int s = 0; s < 4; ++s)
                af[s] = *(const short8*)&As[a_base + s * 16 * LDS_STRIDE + kx];
#pragma unroll
            for (int s = 0; s < 4; ++s)
                bf[s] = *(const short8*)&Bs[b_base + s * 16 * LDS_STRIDE + kx];
#pragma unroll
            for (int a = 0; a < 4; ++a)
#pragma unroll
                for (int b = 0; b < 4; ++b)
                    acc[a][b] = __builtin_amdgcn_mfma_f32_16x16x32_bf16(
                        af[a], bf[b], acc[a][b], 0, 0, 0);
        }
    }

#pragma unroll
    for (int a = 0; a < 4; ++a) {
        const int rb = r0 + wm * 64 + a * 16 + quad * 4;
#pragma unroll
        for (int b = 0; b < 4; ++b) {
            const int i = col0 + wn * 64 + b * 16 + l15;
            const int shift = (i >= 512) ? 1 : 0;
            const int ccol = 2 * i - shift * 1024;
#pragma unroll
            for (int pr = 0; pr < 2; ++pr) {
                const int re = rb + pr * 2;
                const int p  = re >> 1;
                const float h  = Hout[(size_t)p * 1024 + i];
                const float hp = 1.0f - h * h;
                float2 st;
                st.x = hp * acc[a][b][pr * 2];
                st.y = hp * acc[a][b][pr * 2 + 1];
                *(float2*)&out2[(size_t)(re + shift) * 1024 + ccol] = st;
            }
        }
    }
}

extern "C" void kernel_launch(void* const* d_in, const int* in_sizes, int n_in,
                              void* d_out, int out_size, void* d_ws, size_t ws_size,
                              hipStream_t stream) {
    const float* xJx = (const float*)d_in[0];
    const float* W   = (const float*)d_in[1];
    const float* bv  = (const float*)d_in[2];
    float* out = (float*)d_out;

    const int C     = 1024;
    const int rows3 = in_sizes[0] / C;   // 3*pivot
    const int pivot = rows3 / 3;         // 16384

    const size_t szXb = (size_t)pivot * C * 2;          // 32 MB
    const size_t szMb = (size_t)2 * pivot * C * 2;      // 64 MB
    const size_t szWb = (size_t)C * C * 2;              //  2 MB

    if (ws_size >= szXb + szMb + szWb) {
        short* Xb = (short*)d_ws;
        short* Mb = (short*)((char*)d_ws + szXb);
        short* Wb = (short*)((char*)d_ws + szXb + szMb);

        const int nbX = (pivot * C) / 4096;             // 4096
        const int nbG = (pivot * 2 * C) / 4096;         // 8192
        const int nbW = (C * C) / 4096;                 //  256
        cvt_prep<<<dim3(nbX + nbG + nbW), dim3(256), 0, stream>>>(
            xJx, xJx + (size_t)pivot * C, W, Xb, Mb, Wb, nbX, nbG);

        dim3 g1(C / 256, pivot / 256);                  // 4 x 64 = 256 blocks
        k1c_gemm_tanh<<<g1, dim3(512), 0, stream>>>(Xb, Wb, bv, out, C);

        dim3 g2(C / 256, (2 * pivot) / 256);            // 4 x 128 = 512 blocks
        k2c_gemm_jac<<<g2, dim3(512), 0, stream>>>(Mb, Wb, out,
                                                   out + (size_t)pivot * C, C);
    } else {
        dim3 g1(C / 128, pivot / 128);
        k1_gemm_tanh<<<g1, dim3(256), 0, stream>>>(xJx, W, bv, out, C);
        dim3 g2(C / 128, (2 * pivot) / 128);
        k2_gemm_jac<<<g2, dim3(256), 0, stream>>>(xJx + (size_t)pivot * C, W, out,
                                                  out + (size_t)pivot * C, C);
    }
}